// Round 1
// baseline (18501.923 us; speedup 1.0000x reference)
//
#include <hip/hip_runtime.h>
#include <cstdint>
#include <cstddef>

#define BATCH 8
#define SEQ   256
#define HID   1024
#define GATES 4096   // 4*HID
#define VOC   32000

// ---------- helpers ----------
__device__ __forceinline__ float sigf(float x){ return 1.0f/(1.0f + __expf(-x)); }
__device__ __forceinline__ float tanhf_(float x){ return 1.0f - 2.0f/(__expf(2.0f*x) + 1.0f); }

// ---------- init: zero barrier counters + h ping-pong buffers ----------
__global__ void k_init(unsigned* __restrict__ cnt, float* __restrict__ hb){
  int tid = blockIdx.x*blockDim.x + threadIdx.x;
  if (tid < 512) cnt[tid] = 0u;
  for (int i = tid; i < 2*2*BATCH*HID; i += gridDim.x*blockDim.x) hb[i] = 0.0f;
}

// ---------- Wh transpose: WhT[l][n][k] = Wh[l][k][n] ----------
__global__ void k_transpose(const float* __restrict__ Wh, float* __restrict__ WhT){
  __shared__ float tile[32][33];
  int l = blockIdx.z;
  int n0 = blockIdx.x*32, k0 = blockIdx.y*32;
  const float* src = Wh  + (size_t)l*HID*GATES;
  float*       dst = WhT + (size_t)l*GATES*HID;
  int tx = threadIdx.x, ty = threadIdx.y;
  #pragma unroll
  for (int i=0;i<4;i++)
    tile[ty+i*8][tx] = src[(size_t)(k0+ty+i*8)*GATES + n0 + tx];
  __syncthreads();
  #pragma unroll
  for (int i=0;i<4;i++)
    dst[(size_t)(n0+ty+i*8)*HID + k0 + tx] = tile[tx][ty+i*8];
}

// ---------- f32 GEMM: C[r] = Arow(r)·W + b1 (+ b2) ; K fixed = 1024 ----------
// AMODE 0: Arow = A + r*1024 ; AMODE 1: Arow = emb + tokens[(r&7)*SEQ + (r>>3)]*1024
// OMODE 0: Crow = C + r*N    ; OMODE 1: Crow = C + ((r&7)*SEQ + (r>>3))*N
template<int AMODE, int OMODE>
__global__ __launch_bounds__(256) void k_gemm(
    const float* __restrict__ A,
    const float* __restrict__ W,     // [1024][N] row-major
    const float* __restrict__ b1,
    const float* __restrict__ b2,
    const int*   __restrict__ tokens,
    const float* __restrict__ emb,
    float* __restrict__ C, int N)
{
  __shared__ float As[16*132];   // transposed A tile [k][m], padded stride
  __shared__ float Bs[16*128];   // W tile [k][n]
  int tid = threadIdx.x;
  int m0 = blockIdx.y*128, n0 = blockIdx.x*128;

  // A-tile load role: 2 threads per row, one float4x2 each
  int arow = tid >> 1;
  int akq  = (tid & 1) * 8;
  const float* aptr;
  { int gm = m0 + arow;
    if (AMODE==1){ int tt = gm>>3, bb = gm&7; aptr = emb + (size_t)tokens[bb*SEQ+tt]*1024; }
    else          aptr = A + (size_t)gm*1024; }

  // B-tile load role
  int bk = tid >> 5;             // 0..7 (and +8)
  int bn = (tid & 31) * 4;       // 0..124
  const float* wptr = W + (size_t)bk*N + n0 + bn;

  int tx = tid & 15, ty = tid >> 4;
  float acc[8][8];
  #pragma unroll
  for (int i=0;i<8;i++){
    #pragma unroll
    for (int j=0;j<8;j++) acc[i][j] = 0.0f;
  }

  for (int k0=0;k0<1024;k0+=16){
    float4 av0 = *(const float4*)(aptr + k0 + akq);
    float4 av1 = *(const float4*)(aptr + k0 + akq + 4);
    float4 wv0 = *(const float4*)(wptr + (size_t)k0*N);
    float4 wv1 = *(const float4*)(wptr + (size_t)(k0+8)*N);
    __syncthreads();
    As[(akq+0)*132 + arow] = av0.x;
    As[(akq+1)*132 + arow] = av0.y;
    As[(akq+2)*132 + arow] = av0.z;
    As[(akq+3)*132 + arow] = av0.w;
    As[(akq+4)*132 + arow] = av1.x;
    As[(akq+5)*132 + arow] = av1.y;
    As[(akq+6)*132 + arow] = av1.z;
    As[(akq+7)*132 + arow] = av1.w;
    *(float4*)&Bs[bk*128 + bn]     = wv0;
    *(float4*)&Bs[(bk+8)*128 + bn] = wv1;
    __syncthreads();
    #pragma unroll
    for (int k=0;k<16;k++){
      float ra[8], rb[8];
      *(float4*)&ra[0] = *(float4*)&As[k*132 + ty*8];
      *(float4*)&ra[4] = *(float4*)&As[k*132 + ty*8 + 4];
      *(float4*)&rb[0] = *(float4*)&Bs[k*128 + tx*8];
      *(float4*)&rb[4] = *(float4*)&Bs[k*128 + tx*8 + 4];
      #pragma unroll
      for (int i=0;i<8;i++){
        #pragma unroll
        for (int j=0;j<8;j++)
          acc[i][j] = fmaf(ra[i], rb[j], acc[i][j]);
      }
    }
  }

  // epilogue: bias + store
  float bias[8];
  { int nb = n0 + tx*8;
    *(float4*)&bias[0] = *(const float4*)(b1 + nb);
    *(float4*)&bias[4] = *(const float4*)(b1 + nb + 4);
    if (b2){
      float4 c0 = *(const float4*)(b2 + nb);
      float4 c1 = *(const float4*)(b2 + nb + 4);
      bias[0]+=c0.x; bias[1]+=c0.y; bias[2]+=c0.z; bias[3]+=c0.w;
      bias[4]+=c1.x; bias[5]+=c1.y; bias[6]+=c1.z; bias[7]+=c1.w;
    }
  }
  #pragma unroll
  for (int i=0;i<8;i++){
    int gm = m0 + ty*8 + i;
    float* crow;
    if (OMODE==1) crow = C + ((size_t)(gm&7)*SEQ + (gm>>3))*N;
    else          crow = C + (size_t)gm*N;
    float4 o0, o1;
    o0.x = acc[i][0]+bias[0]; o0.y = acc[i][1]+bias[1];
    o0.z = acc[i][2]+bias[2]; o0.w = acc[i][3]+bias[3];
    o1.x = acc[i][4]+bias[4]; o1.y = acc[i][5]+bias[5];
    o1.z = acc[i][6]+bias[6]; o1.w = acc[i][7]+bias[7];
    *(float4*)(crow + n0 + tx*8)     = o0;
    *(float4*)(crow + n0 + tx*8 + 4) = o1;
  }
}

// ---------- persistent recurrence: 256 blocks, 4 hidden units each ----------
// G: [2048][4096] = x@Wx + bx + bh (bias pre-folded). WhT: this layer's [4096][1024].
// hb: this layer's ping-pong h [2][8][1024] (buf0 zeroed). cnt: 256 one-shot counters.
__global__ __launch_bounds__(256) void k_rec(
    const float* __restrict__ G,
    const float* __restrict__ WhT,
    float* __restrict__ Hout,        // [2048][1024], row = t*8+b
    float* __restrict__ hb,
    unsigned* __restrict__ cnt,
    int nblk)
{
  extern __shared__ float lds[];
  float* Wl  = lds;            // [16][1024] f32 gate columns
  float* gsc = lds + 16*1024;  // [2][8][16] partial dots
  int tid = threadIdx.x;
  int u0 = blockIdx.x*4;       // 4 hidden units per block

  // stage 16 gate columns (g*1024 + u0 + j) into LDS
  for (int c=0;c<16;c++){
    int col = (c>>2)*1024 + u0 + (c&3);
    const float* src = WhT + (size_t)col*1024;
    *(float4*)&Wl[c*1024 + tid*4] = *(const float4*)(src + tid*4);
  }
  __syncthreads();

  int ks = tid >> 7, bb = (tid >> 4) & 7, cc = tid & 15;  // dot role
  int cb = tid >> 2, cj = tid & 3;                         // cell role (tid<32)
  float creg = 0.0f;

  for (int t=0;t<SEQ;t++){
    // prefetch this step's precomputed x-gates for cell threads (overlaps dot loop)
    float gpre0=0.f,gpre1=0.f,gpre2=0.f,gpre3=0.f;
    if (tid < 32){
      const float* gp = G + ((size_t)t*8 + cb)*GATES + u0 + cj;
      gpre0 = gp[0]; gpre1 = gp[1024]; gpre2 = gp[2048]; gpre3 = gp[3072];
    }
    const float* hr = hb + (t&1)*(BATCH*HID) + bb*HID + ks*512;
    const float* wl = Wl + cc*1024 + ks*512;
    float acc = 0.0f;
    #pragma unroll 8
    for (int k=0;k<512;k+=4){
      float4 hv = *(const float4*)(hr + k);
      float4 wv = *(const float4*)(wl + k);
      acc = fmaf(hv.x, wv.x, acc);
      acc = fmaf(hv.y, wv.y, acc);
      acc = fmaf(hv.z, wv.z, acc);
      acc = fmaf(hv.w, wv.w, acc);
    }
    gsc[ks*128 + bb*16 + cc] = acc;
    __syncthreads();
    if (tid < 32){
      float xi = gpre0 + gsc[cb*16 + 0  + cj] + gsc[128 + cb*16 + 0  + cj];
      float xf = gpre1 + gsc[cb*16 + 4  + cj] + gsc[128 + cb*16 + 4  + cj];
      float xg = gpre2 + gsc[cb*16 + 8  + cj] + gsc[128 + cb*16 + 8  + cj];
      float xo = gpre3 + gsc[cb*16 + 12 + cj] + gsc[128 + cb*16 + 12 + cj];
      float iv = sigf(xi), fv = sigf(xf), ov = sigf(xo), gv = tanhf_(xg);
      creg = fv*creg + iv*gv;
      float hv = ov * tanhf_(creg);
      hb[((t+1)&1)*(BATCH*HID) + cb*HID + u0 + cj] = hv;
      Hout[((size_t)t*8 + cb)*HID + u0 + cj] = hv;
    }
    __syncthreads();
    // one-shot grid barrier for phase t
    if (tid == 0){
      __threadfence();
      __hip_atomic_fetch_add(&cnt[t], 1u, __ATOMIC_ACQ_REL, __HIP_MEMORY_SCOPE_AGENT);
      int spins = 0;
      while (__hip_atomic_load(&cnt[t], __ATOMIC_ACQUIRE, __HIP_MEMORY_SCOPE_AGENT) < (unsigned)nblk){
        __builtin_amdgcn_s_sleep(1);
        if (++spins > 4000000) break;   // safety valve: degrade to wrong answer, not hang
      }
    }
    __syncthreads();
  }
}

extern "C" void kernel_launch(void* const* d_in, const int* in_sizes, int n_in,
                              void* d_out, int out_size, void* d_ws, size_t ws_size,
                              hipStream_t stream) {
  const int*   tokens = (const int*)d_in[0];
  const float* emb = (const float*)d_in[1];
  const float* Wx  = (const float*)d_in[2];
  const float* bx  = (const float*)d_in[3];
  const float* Wh  = (const float*)d_in[4];
  const float* bh  = (const float*)d_in[5];
  const float* Wd  = (const float*)d_in[6];
  const float* bd  = (const float*)d_in[7];
  float* out = (float*)d_out;
  float* ws  = (float*)d_ws;

  // ws layout (floats): G 8388608 | H0 2097152 | Tops 2097152 | WhT 8388608 | hb 32768 | cnt 512
  float* G    = ws;
  float* H0   = ws + (size_t)8388608;
  float* Tops = ws + (size_t)10485760;
  float* WhT  = ws + (size_t)12582912;
  float* hb   = ws + (size_t)20971520;
  unsigned* cnt = (unsigned*)(ws + (size_t)21004288);

  (void)hipFuncSetAttribute((const void*)k_rec,
        hipFuncAttributeMaxDynamicSharedMemorySize, 66560);

  k_init<<<32,256,0,stream>>>(cnt, hb);
  k_transpose<<<dim3(128,32,2), dim3(32,8), 0, stream>>>(Wh, WhT);

  // layer 0: G0 = emb[tok] @ Wx0 + (bx0+bh0)
  k_gemm<1,0><<<dim3(32,16),256,0,stream>>>(nullptr, Wx, bx, bh, tokens, emb, G, GATES);
  k_rec<<<256,256,66560,stream>>>(G, WhT, H0, hb, cnt, 256);

  // layer 1: G1 = H0 @ Wx1 + (bx1+bh1)
  k_gemm<0,0><<<dim3(32,16),256,0,stream>>>(H0, Wx + (size_t)1024*GATES, bx+GATES, bh+GATES,
                                            nullptr, nullptr, G, GATES);
  k_rec<<<256,256,66560,stream>>>(G, WhT + (size_t)GATES*HID, Tops, hb + 2*BATCH*HID,
                                  cnt + 256, 256);

  // final projection: out[b][t][v] = Tops[t*8+b] @ Wd + bd
  k_gemm<0,1><<<dim3(250,16),256,0,stream>>>(Tops, Wd, bd, nullptr, nullptr, nullptr, out, VOC);
}

// Round 2
// 13376.245 us; speedup vs baseline: 1.3832x; 1.3832x over previous
//
#include <hip/hip_runtime.h>
#include <cstdint>
#include <cstddef>

#define BATCH 8
#define SEQ   256
#define HID   1024
#define GATES 4096   // 4*HID
#define VOC   32000

// ---------- helpers ----------
__device__ __forceinline__ float sigf(float x){ return 1.0f/(1.0f + __expf(-x)); }
__device__ __forceinline__ float tanhf_(float x){ return 1.0f - 2.0f/(__expf(2.0f*x) + 1.0f); }

// ---------- init: zero barrier counters + h ping-pong buffers ----------
__global__ void k_init(unsigned* __restrict__ cnt, float* __restrict__ hb){
  int tid = blockIdx.x*blockDim.x + threadIdx.x;
  if (tid < 512) cnt[tid] = 0u;
  for (int i = tid; i < 2*2*BATCH*HID; i += gridDim.x*blockDim.x) hb[i] = 0.0f;
}

// ---------- Wh transpose: WhT[l][n][k] = Wh[l][k][n] ----------
__global__ void k_transpose(const float* __restrict__ Wh, float* __restrict__ WhT){
  __shared__ float tile[32][33];
  int l = blockIdx.z;
  int n0 = blockIdx.x*32, k0 = blockIdx.y*32;
  const float* src = Wh  + (size_t)l*HID*GATES;
  float*       dst = WhT + (size_t)l*GATES*HID;
  int tx = threadIdx.x, ty = threadIdx.y;
  #pragma unroll
  for (int i=0;i<4;i++)
    tile[ty+i*8][tx] = src[(size_t)(k0+ty+i*8)*GATES + n0 + tx];
  __syncthreads();
  #pragma unroll
  for (int i=0;i<4;i++)
    dst[(size_t)(n0+ty+i*8)*HID + k0 + tx] = tile[tx][ty+i*8];
}

// ---------- f32 GEMM: C[r] = Arow(r)·W + b1 (+ b2) ; K fixed = 1024 ----------
template<int AMODE, int OMODE>
__global__ __launch_bounds__(256) void k_gemm(
    const float* __restrict__ A,
    const float* __restrict__ W,     // [1024][N] row-major
    const float* __restrict__ b1,
    const float* __restrict__ b2,
    const int*   __restrict__ tokens,
    const float* __restrict__ emb,
    float* __restrict__ C, int N)
{
  __shared__ float As[16*132];   // transposed A tile [k][m], padded stride
  __shared__ float Bs[16*128];   // W tile [k][n]
  int tid = threadIdx.x;
  int m0 = blockIdx.y*128, n0 = blockIdx.x*128;

  int arow = tid >> 1;
  int akq  = (tid & 1) * 8;
  const float* aptr;
  { int gm = m0 + arow;
    if (AMODE==1){ int tt = gm>>3, bb = gm&7; aptr = emb + (size_t)tokens[bb*SEQ+tt]*1024; }
    else          aptr = A + (size_t)gm*1024; }

  int bk = tid >> 5;
  int bn = (tid & 31) * 4;
  const float* wptr = W + (size_t)bk*N + n0 + bn;

  int tx = tid & 15, ty = tid >> 4;
  float acc[8][8];
  #pragma unroll
  for (int i=0;i<8;i++){
    #pragma unroll
    for (int j=0;j<8;j++) acc[i][j] = 0.0f;
  }

  for (int k0=0;k0<1024;k0+=16){
    float4 av0 = *(const float4*)(aptr + k0 + akq);
    float4 av1 = *(const float4*)(aptr + k0 + akq + 4);
    float4 wv0 = *(const float4*)(wptr + (size_t)k0*N);
    float4 wv1 = *(const float4*)(wptr + (size_t)(k0+8)*N);
    __syncthreads();
    As[(akq+0)*132 + arow] = av0.x;
    As[(akq+1)*132 + arow] = av0.y;
    As[(akq+2)*132 + arow] = av0.z;
    As[(akq+3)*132 + arow] = av0.w;
    As[(akq+4)*132 + arow] = av1.x;
    As[(akq+5)*132 + arow] = av1.y;
    As[(akq+6)*132 + arow] = av1.z;
    As[(akq+7)*132 + arow] = av1.w;
    *(float4*)&Bs[bk*128 + bn]     = wv0;
    *(float4*)&Bs[(bk+8)*128 + bn] = wv1;
    __syncthreads();
    #pragma unroll
    for (int k=0;k<16;k++){
      float ra[8], rb[8];
      *(float4*)&ra[0] = *(float4*)&As[k*132 + ty*8];
      *(float4*)&ra[4] = *(float4*)&As[k*132 + ty*8 + 4];
      *(float4*)&rb[0] = *(float4*)&Bs[k*128 + tx*8];
      *(float4*)&rb[4] = *(float4*)&Bs[k*128 + tx*8 + 4];
      #pragma unroll
      for (int i=0;i<8;i++){
        #pragma unroll
        for (int j=0;j<8;j++)
          acc[i][j] = fmaf(ra[i], rb[j], acc[i][j]);
      }
    }
  }

  float bias[8];
  { int nb = n0 + tx*8;
    *(float4*)&bias[0] = *(const float4*)(b1 + nb);
    *(float4*)&bias[4] = *(const float4*)(b1 + nb + 4);
    if (b2){
      float4 c0 = *(const float4*)(b2 + nb);
      float4 c1 = *(const float4*)(b2 + nb + 4);
      bias[0]+=c0.x; bias[1]+=c0.y; bias[2]+=c0.z; bias[3]+=c0.w;
      bias[4]+=c1.x; bias[5]+=c1.y; bias[6]+=c1.z; bias[7]+=c1.w;
    }
  }
  #pragma unroll
  for (int i=0;i<8;i++){
    int gm = m0 + ty*8 + i;
    float* crow;
    if (OMODE==1) crow = C + ((size_t)(gm&7)*SEQ + (gm>>3))*N;
    else          crow = C + (size_t)gm*N;
    float4 o0, o1;
    o0.x = acc[i][0]+bias[0]; o0.y = acc[i][1]+bias[1];
    o0.z = acc[i][2]+bias[2]; o0.w = acc[i][3]+bias[3];
    o1.x = acc[i][4]+bias[4]; o1.y = acc[i][5]+bias[5];
    o1.z = acc[i][6]+bias[6]; o1.w = acc[i][7]+bias[7];
    *(float4*)(crow + n0 + tx*8)     = o0;
    *(float4*)(crow + n0 + tx*8 + 4) = o1;
  }
}

// ---------- persistent recurrence v2: conflict-free LDS, h staged to LDS ----------
// Per block: 4 hidden units (16 gate columns). LDS layout (floats):
//   Wl[16][1028]  @0       : gate columns, stride 1028 -> col c maps to bank group 4c%32
//   hl[8][1028]   @16448   : h staged per step, batch b -> bank group 4b%32
//   gsc[4][64][2] @24672   : per-wave partial dots
//   gates[8][20]  @25184   : reduced gate pre-activations
__global__ __launch_bounds__(256) void k_rec(
    const float* __restrict__ G,
    const float* __restrict__ WhT,
    float* __restrict__ Hout,        // [2048][1024], row = t*8+b
    float* __restrict__ hb,          // ping-pong [2][8][1024]
    unsigned* __restrict__ cnt,
    int nblk)
{
  extern __shared__ float lds[];
  float* Wl    = lds;
  float* hl    = lds + 16448;
  float* gsc   = lds + 24672;
  float* gates = lds + 25184;
  int tid = threadIdx.x;
  int u0 = blockIdx.x*4;

  // one-time: stage 16 gate columns (c = g*4+j) into LDS, coalesced global reads
  {
    int c = tid >> 4, ks = tid & 15;
    const float* src = WhT + ((size_t)(c>>2)*1024 + u0 + (c&3))*1024 + ks*64;
    float* dst = Wl + c*1028 + ks*64;
    #pragma unroll
    for (int i=0;i<16;i++)
      *(float4*)(dst + i*4) = *(const float4*)(src + i*4);
  }

  const int wv = tid >> 6, ln = tid & 63;
  const int db = ln >> 3, dc = ln & 7;         // dot roles: batch, col (and col+8)
  const int kbase = wv*256;                    // wave's K-range
  const int sb = tid & 7, sk = (tid >> 3)*32;  // h-staging roles
  const int cb = tid >> 2, cj = tid & 3;       // cell roles (tid<32)
  float creg = 0.0f;

  for (int t=0;t<SEQ;t++){
    const float* hcur = hb + (t&1)*8192;
    // stage h[8][1024] -> hl (32KB from L2, read once per block per step)
    {
      const float* src = hcur + sb*1024 + sk;
      float* dst = hl + sb*1028 + sk;
      #pragma unroll
      for (int i=0;i<8;i++)
        *(float4*)(dst + i*4) = *(const float4*)(src + i*4);
    }
    // prefetch x-gate pre-activations (consumed ~2000 cyc later)
    float gp0=0.f,gp1=0.f,gp2=0.f,gp3=0.f;
    if (tid < 32){
      const float* gp = G + ((size_t)t*8 + cb)*GATES + u0 + cj;
      gp0 = gp[0]; gp1 = gp[1024]; gp2 = gp[2048]; gp3 = gp[3072];
    }
    __syncthreads();

    // dot: cols dc and dc+8 for batch db over K [kbase, kbase+256)
    float a0 = 0.f, a1 = 0.f;
    const float* hp = hl + db*1028 + kbase;
    const float* w0 = Wl + dc*1028 + kbase;
    const float* w1 = Wl + (dc+8)*1028 + kbase;
    #pragma unroll 4
    for (int k=0;k<256;k+=4){
      float4 hv = *(const float4*)(hp + k);
      float4 x0 = *(const float4*)(w0 + k);
      float4 x1 = *(const float4*)(w1 + k);
      a0 = fmaf(hv.x,x0.x,a0); a0 = fmaf(hv.y,x0.y,a0);
      a0 = fmaf(hv.z,x0.z,a0); a0 = fmaf(hv.w,x0.w,a0);
      a1 = fmaf(hv.x,x1.x,a1); a1 = fmaf(hv.y,x1.y,a1);
      a1 = fmaf(hv.z,x1.z,a1); a1 = fmaf(hv.w,x1.w,a1);
    }
    gsc[wv*128 + ln*2 + 0] = a0;
    gsc[wv*128 + ln*2 + 1] = a1;
    __syncthreads();

    // reduce 4 wave-partials per (b,c)
    if (tid < 128){
      int b = tid >> 4, c = tid & 15;
      int l2 = (b*8 + (c & 7))*2 + (c >> 3);
      gates[b*20 + c] = gsc[l2] + gsc[128 + l2] + gsc[256 + l2] + gsc[384 + l2];
    }
    __syncthreads();

    // cell update: thread (cb, cj) owns (batch cb, unit u0+cj)
    if (tid < 32){
      float xi = gp0 + gates[cb*20 + 0  + cj];
      float xf = gp1 + gates[cb*20 + 4  + cj];
      float xg = gp2 + gates[cb*20 + 8  + cj];
      float xo = gp3 + gates[cb*20 + 12 + cj];
      float iv = sigf(xi), fv = sigf(xf), ov = sigf(xo), gv = tanhf_(xg);
      creg = fv*creg + iv*gv;
      float hv = ov * tanhf_(creg);
      hb[((t+1)&1)*8192 + cb*1024 + u0 + cj] = hv;
      Hout[((size_t)t*8 + cb)*HID + u0 + cj] = hv;
    }
    __syncthreads();

    // one-shot grid barrier for phase t
    if (tid == 0){
      __threadfence();
      __hip_atomic_fetch_add(&cnt[t], 1u, __ATOMIC_ACQ_REL, __HIP_MEMORY_SCOPE_AGENT);
      int spins = 0;
      while (__hip_atomic_load(&cnt[t], __ATOMIC_ACQUIRE, __HIP_MEMORY_SCOPE_AGENT) < (unsigned)nblk){
        __builtin_amdgcn_s_sleep(1);
        if (++spins > 8000000) break;   // safety valve: wrong answer beats a hang
      }
    }
    __syncthreads();
  }
}

extern "C" void kernel_launch(void* const* d_in, const int* in_sizes, int n_in,
                              void* d_out, int out_size, void* d_ws, size_t ws_size,
                              hipStream_t stream) {
  const int*   tokens = (const int*)d_in[0];
  const float* emb = (const float*)d_in[1];
  const float* Wx  = (const float*)d_in[2];
  const float* bx  = (const float*)d_in[3];
  const float* Wh  = (const float*)d_in[4];
  const float* bh  = (const float*)d_in[5];
  const float* Wd  = (const float*)d_in[6];
  const float* bd  = (const float*)d_in[7];
  float* out = (float*)d_out;
  float* ws  = (float*)d_ws;

  // ws layout (floats): G 8388608 | H0 2097152 | Tops 2097152 | WhT 8388608 | hb 32768 | cnt 512
  float* G    = ws;
  float* H0   = ws + (size_t)8388608;
  float* Tops = ws + (size_t)10485760;
  float* WhT  = ws + (size_t)12582912;
  float* hb   = ws + (size_t)20971520;
  unsigned* cnt = (unsigned*)(ws + (size_t)21004288);

  (void)hipFuncSetAttribute((const void*)k_rec,
        hipFuncAttributeMaxDynamicSharedMemorySize, 101376);

  k_init<<<32,256,0,stream>>>(cnt, hb);
  k_transpose<<<dim3(128,32,2), dim3(32,8), 0, stream>>>(Wh, WhT);

  // layer 0: G0 = emb[tok] @ Wx0 + (bx0+bh0)
  k_gemm<1,0><<<dim3(32,16),256,0,stream>>>(nullptr, Wx, bx, bh, tokens, emb, G, GATES);
  k_rec<<<256,256,101376,stream>>>(G, WhT, H0, hb, cnt, 256);

  // layer 1: G1 = H0 @ Wx1 + (bx1+bh1)
  k_gemm<0,0><<<dim3(32,16),256,0,stream>>>(H0, Wx + (size_t)1024*GATES, bx+GATES, bh+GATES,
                                            nullptr, nullptr, G, GATES);
  k_rec<<<256,256,101376,stream>>>(G, WhT + (size_t)GATES*HID, Tops, hb + 2*BATCH*HID,
                                  cnt + 256, 256);

  // final projection: out[b][t][v] = Tops[t*8+b] @ Wd + bd
  k_gemm<0,1><<<dim3(250,16),256,0,stream>>>(Tops, Wd, bd, nullptr, nullptr, nullptr, out, VOC);
}

// Round 3
// 11996.394 us; speedup vs baseline: 1.5423x; 1.1150x over previous
//
#include <hip/hip_runtime.h>
#include <cstdint>
#include <cstddef>

#define BATCH 8
#define SEQ   256
#define HID   1024
#define GATES 4096   // 4*HID
#define VOC   32000

// ---------- helpers ----------
__device__ __forceinline__ float sigf(float x){ return 1.0f/(1.0f + __expf(-x)); }
__device__ __forceinline__ float tanhf_(float x){ return 1.0f - 2.0f/(__expf(2.0f*x) + 1.0f); }

// ---------- init: zero barrier counters + h ping-pong buffers ----------
// grp: [512][8][16] uints (64B slots), mst: [512][16] uints
__global__ void k_init(unsigned* __restrict__ grp, unsigned* __restrict__ mst,
                       float* __restrict__ hb){
  int tid = blockIdx.x*blockDim.x + threadIdx.x;
  int nt = gridDim.x*blockDim.x;
  for (int i = tid; i < 512*8*16; i += nt) grp[i] = 0u;
  for (int i = tid; i < 512*16;   i += nt) mst[i] = 0u;
  for (int i = tid; i < 2*2*BATCH*HID; i += nt) hb[i] = 0.0f;
}

// ---------- Wh transpose: WhT[l][n][k] = Wh[l][k][n] ----------
__global__ void k_transpose(const float* __restrict__ Wh, float* __restrict__ WhT){
  __shared__ float tile[32][33];
  int l = blockIdx.z;
  int n0 = blockIdx.x*32, k0 = blockIdx.y*32;
  const float* src = Wh  + (size_t)l*HID*GATES;
  float*       dst = WhT + (size_t)l*GATES*HID;
  int tx = threadIdx.x, ty = threadIdx.y;
  #pragma unroll
  for (int i=0;i<4;i++)
    tile[ty+i*8][tx] = src[(size_t)(k0+ty+i*8)*GATES + n0 + tx];
  __syncthreads();
  #pragma unroll
  for (int i=0;i<4;i++)
    dst[(size_t)(n0+ty+i*8)*HID + k0 + tx] = tile[tx][ty+i*8];
}

// ---------- f32 GEMM: C[r] = Arow(r)·W + b1 (+ b2) ; K fixed = 1024 ----------
template<int AMODE, int OMODE>
__global__ __launch_bounds__(256) void k_gemm(
    const float* __restrict__ A,
    const float* __restrict__ W,     // [1024][N] row-major
    const float* __restrict__ b1,
    const float* __restrict__ b2,
    const int*   __restrict__ tokens,
    const float* __restrict__ emb,
    float* __restrict__ C, int N)
{
  __shared__ float As[16*132];   // transposed A tile [k][m], padded stride
  __shared__ float Bs[16*128];   // W tile [k][n]
  int tid = threadIdx.x;
  int m0 = blockIdx.y*128, n0 = blockIdx.x*128;

  int arow = tid >> 1;
  int akq  = (tid & 1) * 8;
  const float* aptr;
  { int gm = m0 + arow;
    if (AMODE==1){ int tt = gm>>3, bb = gm&7; aptr = emb + (size_t)tokens[bb*SEQ+tt]*1024; }
    else          aptr = A + (size_t)gm*1024; }

  int bk = tid >> 5;
  int bn = (tid & 31) * 4;
  const float* wptr = W + (size_t)bk*N + n0 + bn;

  int tx = tid & 15, ty = tid >> 4;
  float acc[8][8];
  #pragma unroll
  for (int i=0;i<8;i++){
    #pragma unroll
    for (int j=0;j<8;j++) acc[i][j] = 0.0f;
  }

  for (int k0=0;k0<1024;k0+=16){
    float4 av0 = *(const float4*)(aptr + k0 + akq);
    float4 av1 = *(const float4*)(aptr + k0 + akq + 4);
    float4 wv0 = *(const float4*)(wptr + (size_t)k0*N);
    float4 wv1 = *(const float4*)(wptr + (size_t)(k0+8)*N);
    __syncthreads();
    As[(akq+0)*132 + arow] = av0.x;
    As[(akq+1)*132 + arow] = av0.y;
    As[(akq+2)*132 + arow] = av0.z;
    As[(akq+3)*132 + arow] = av0.w;
    As[(akq+4)*132 + arow] = av1.x;
    As[(akq+5)*132 + arow] = av1.y;
    As[(akq+6)*132 + arow] = av1.z;
    As[(akq+7)*132 + arow] = av1.w;
    *(float4*)&Bs[bk*128 + bn]     = wv0;
    *(float4*)&Bs[(bk+8)*128 + bn] = wv1;
    __syncthreads();
    #pragma unroll
    for (int k=0;k<16;k++){
      float ra[8], rb[8];
      *(float4*)&ra[0] = *(float4*)&As[k*132 + ty*8];
      *(float4*)&ra[4] = *(float4*)&As[k*132 + ty*8 + 4];
      *(float4*)&rb[0] = *(float4*)&Bs[k*128 + tx*8];
      *(float4*)&rb[4] = *(float4*)&Bs[k*128 + tx*8 + 4];
      #pragma unroll
      for (int i=0;i<8;i++){
        #pragma unroll
        for (int j=0;j<8;j++)
          acc[i][j] = fmaf(ra[i], rb[j], acc[i][j]);
      }
    }
  }

  float bias[8];
  { int nb = n0 + tx*8;
    *(float4*)&bias[0] = *(const float4*)(b1 + nb);
    *(float4*)&bias[4] = *(const float4*)(b1 + nb + 4);
    if (b2){
      float4 c0 = *(const float4*)(b2 + nb);
      float4 c1 = *(const float4*)(b2 + nb + 4);
      bias[0]+=c0.x; bias[1]+=c0.y; bias[2]+=c0.z; bias[3]+=c0.w;
      bias[4]+=c1.x; bias[5]+=c1.y; bias[6]+=c1.z; bias[7]+=c1.w;
    }
  }
  #pragma unroll
  for (int i=0;i<8;i++){
    int gm = m0 + ty*8 + i;
    float* crow;
    if (OMODE==1) crow = C + ((size_t)(gm&7)*SEQ + (gm>>3))*N;
    else          crow = C + (size_t)gm*N;
    float4 o0, o1;
    o0.x = acc[i][0]+bias[0]; o0.y = acc[i][1]+bias[1];
    o0.z = acc[i][2]+bias[2]; o0.w = acc[i][3]+bias[3];
    o1.x = acc[i][4]+bias[4]; o1.y = acc[i][5]+bias[5];
    o1.z = acc[i][6]+bias[6]; o1.w = acc[i][7]+bias[7];
    *(float4*)(crow + n0 + tx*8)     = o0;
    *(float4*)(crow + n0 + tx*8 + 4) = o1;
  }
}

// ---------- persistent recurrence v3: hierarchical grid barrier ----------
// Per block: 4 hidden units (16 gate columns). LDS layout (floats):
//   Wl[16][1028] @0 | hl[8][1028] @16448 | gsc[4][64][2] @24672
// Barrier: grp[(t*8+g)*16] (g=blockIdx&7, 32 blocks each), 32nd arriver bumps
// mst[t*16]; all spin on mst==8. Max same-address RMW chain: 32.
__global__ __launch_bounds__(256) void k_rec(
    const float* __restrict__ G,
    const float* __restrict__ WhT,
    float* __restrict__ Hout,        // [2048][1024], row = t*8+b
    float* __restrict__ hb,          // ping-pong [2][8][1024]
    unsigned* __restrict__ grp,
    unsigned* __restrict__ mst)
{
  extern __shared__ float lds[];
  float* Wl  = lds;
  float* hl  = lds + 16448;
  float* gsc = lds + 24672;
  int tid = threadIdx.x;
  int u0 = blockIdx.x*4;
  const int g = blockIdx.x & 7;

  // one-time: stage 16 gate columns (c = gate*4+unit) into LDS
  {
    int c = tid >> 4, ks = tid & 15;
    const float* src = WhT + ((size_t)(c>>2)*1024 + u0 + (c&3))*1024 + ks*64;
    float* dst = Wl + c*1028 + ks*64;
    #pragma unroll
    for (int i=0;i<16;i++)
      *(float4*)(dst + i*4) = *(const float4*)(src + i*4);
  }

  const int wv = tid >> 6, ln = tid & 63;
  const int db = ln >> 3, dc = ln & 7;         // dot roles: batch, col (and col+8)
  const int kbase = wv*256;
  const int sb = tid & 7, sk = (tid >> 3)*32;  // h-staging roles
  const int cb = tid >> 2, cj = tid & 3;       // cell roles (tid<32)
  float creg = 0.0f;

  for (int t=0;t<SEQ;t++){
    const float* hcur = hb + (t&1)*8192;
    // stage h[8][1024] -> hl
    {
      const float* src = hcur + sb*1024 + sk;
      float* dst = hl + sb*1028 + sk;
      #pragma unroll
      for (int i=0;i<8;i++)
        *(float4*)(dst + i*4) = *(const float4*)(src + i*4);
    }
    // prefetch x-gate pre-activations (consumed after dot loop)
    float gp0=0.f,gp1=0.f,gp2=0.f,gp3=0.f;
    if (tid < 32){
      const float* gp = G + ((size_t)t*8 + cb)*GATES + u0 + cj;
      gp0 = gp[0]; gp1 = gp[1024]; gp2 = gp[2048]; gp3 = gp[3072];
    }
    __syncthreads();

    // dot: cols dc and dc+8 for batch db over K [kbase, kbase+256)
    float a0 = 0.f, a1 = 0.f;
    const float* hp = hl + db*1028 + kbase;
    const float* w0 = Wl + dc*1028 + kbase;
    const float* w1 = Wl + (dc+8)*1028 + kbase;
    #pragma unroll 4
    for (int k=0;k<256;k+=4){
      float4 hv = *(const float4*)(hp + k);
      float4 x0 = *(const float4*)(w0 + k);
      float4 x1 = *(const float4*)(w1 + k);
      a0 = fmaf(hv.x,x0.x,a0); a0 = fmaf(hv.y,x0.y,a0);
      a0 = fmaf(hv.z,x0.z,a0); a0 = fmaf(hv.w,x0.w,a0);
      a1 = fmaf(hv.x,x1.x,a1); a1 = fmaf(hv.y,x1.y,a1);
      a1 = fmaf(hv.z,x1.z,a1); a1 = fmaf(hv.w,x1.w,a1);
    }
    gsc[wv*128 + ln*2 + 0] = a0;
    gsc[wv*128 + ln*2 + 1] = a1;
    __syncthreads();

    // cell update: thread (cb, cj) owns (batch cb, unit u0+cj); reduce inline
    if (tid < 32){
      int b0 = (cb*8 + cj)*2, b1i = (cb*8 + 4 + cj)*2;
      float xi = gp0, xf = gp1, xg = gp2, xo = gp3;
      #pragma unroll
      for (int w=0;w<4;w++){
        xi += gsc[w*128 + b0];
        xf += gsc[w*128 + b1i];
        xg += gsc[w*128 + b0 + 1];
        xo += gsc[w*128 + b1i + 1];
      }
      float iv = sigf(xi), fv = sigf(xf), ov = sigf(xo), gv = tanhf_(xg);
      creg = fv*creg + iv*gv;
      float hv = ov * tanhf_(creg);
      hb[((t+1)&1)*8192 + cb*1024 + u0 + cj] = hv;
      Hout[((size_t)t*8 + cb)*HID + u0 + cj] = hv;
    }

    // hierarchical one-shot grid barrier for phase t
    if (tid == 0){
      __threadfence();
      unsigned old = __hip_atomic_fetch_add(&grp[(t*8+g)*16], 1u,
                        __ATOMIC_ACQ_REL, __HIP_MEMORY_SCOPE_AGENT);
      if (old == 31u)
        __hip_atomic_fetch_add(&mst[t*16], 1u,
                        __ATOMIC_ACQ_REL, __HIP_MEMORY_SCOPE_AGENT);
      int spins = 0;
      while (__hip_atomic_load(&mst[t*16], __ATOMIC_ACQUIRE,
                               __HIP_MEMORY_SCOPE_AGENT) < 8u){
        __builtin_amdgcn_s_sleep(1);
        if (++spins > 8000000) break;   // safety valve: wrong answer beats a hang
      }
    }
    __syncthreads();
  }
}

extern "C" void kernel_launch(void* const* d_in, const int* in_sizes, int n_in,
                              void* d_out, int out_size, void* d_ws, size_t ws_size,
                              hipStream_t stream) {
  const int*   tokens = (const int*)d_in[0];
  const float* emb = (const float*)d_in[1];
  const float* Wx  = (const float*)d_in[2];
  const float* bx  = (const float*)d_in[3];
  const float* Wh  = (const float*)d_in[4];
  const float* bh  = (const float*)d_in[5];
  const float* Wd  = (const float*)d_in[6];
  const float* bd  = (const float*)d_in[7];
  float* out = (float*)d_out;
  float* ws  = (float*)d_ws;

  // ws layout (floats): G 8388608 | H0 2097152 | Tops 2097152 | WhT 8388608 |
  //                     hb 32768 | grp 65536 | mst 8192
  float* G    = ws;
  float* H0   = ws + (size_t)8388608;
  float* Tops = ws + (size_t)10485760;
  float* WhT  = ws + (size_t)12582912;
  float* hb   = ws + (size_t)20971520;
  unsigned* grp = (unsigned*)(ws + (size_t)21004288);
  unsigned* mst = (unsigned*)(ws + (size_t)21069824);

  (void)hipFuncSetAttribute((const void*)k_rec,
        hipFuncAttributeMaxDynamicSharedMemorySize, 101376);

  k_init<<<32,256,0,stream>>>(grp, mst, hb);
  k_transpose<<<dim3(128,32,2), dim3(32,8), 0, stream>>>(Wh, WhT);

  // layer 0: G0 = emb[tok] @ Wx0 + (bx0+bh0)
  k_gemm<1,0><<<dim3(32,16),256,0,stream>>>(nullptr, Wx, bx, bh, tokens, emb, G, GATES);
  k_rec<<<256,256,101376,stream>>>(G, WhT, H0, hb, grp, mst);

  // layer 1: G1 = H0 @ Wx1 + (bx1+bh1)
  k_gemm<0,0><<<dim3(32,16),256,0,stream>>>(H0, Wx + (size_t)1024*GATES, bx+GATES, bh+GATES,
                                            nullptr, nullptr, G, GATES);
  k_rec<<<256,256,101376,stream>>>(G, WhT + (size_t)GATES*HID, Tops, hb + 2*BATCH*HID,
                                  grp + 256*8*16, mst + 256*16);

  // final projection: out[b][t][v] = Tops[t*8+b] @ Wd + bd
  k_gemm<0,1><<<dim3(250,16),256,0,stream>>>(Tops, Wd, bd, nullptr, nullptr, nullptr, out, VOC);
}

// Round 5
// 8723.204 us; speedup vs baseline: 2.1210x; 1.3752x over previous
//
#include <hip/hip_runtime.h>
#include <cstdint>
#include <cstddef>

#define BATCH 8
#define SEQ   256
#define HID   1024
#define GATES 4096   // 4*HID
#define VOC   32000

// ---------- helpers ----------
__device__ __forceinline__ float sigf(float x){ return 1.0f/(1.0f + __expf(-x)); }
__device__ __forceinline__ float tanhf_(float x){ return 1.0f - 2.0f/(__expf(2.0f*x) + 1.0f); }

// ---------- init: zero barrier counters + h ping-pong buffers ----------
// grp: 2x[256][8][16] uints (64B slots), mst: 2x[256][32] uints (128B slots)
__global__ void k_init(unsigned* __restrict__ grp, unsigned* __restrict__ mst,
                       float* __restrict__ hb){
  int tid = blockIdx.x*blockDim.x + threadIdx.x;
  int nt = gridDim.x*blockDim.x;
  for (int i = tid; i < 2*256*8*16; i += nt) grp[i] = 0u;
  for (int i = tid; i < 2*256*32;   i += nt) mst[i] = 0u;
  for (int i = tid; i < 2*2*BATCH*HID; i += nt) hb[i] = 0.0f;
}

// ---------- Wh transpose: WhT[l][n][k] = Wh[l][k][n] ----------
__global__ void k_transpose(const float* __restrict__ Wh, float* __restrict__ WhT){
  __shared__ float tile[32][33];
  int l = blockIdx.z;
  int n0 = blockIdx.x*32, k0 = blockIdx.y*32;
  const float* src = Wh  + (size_t)l*HID*GATES;
  float*       dst = WhT + (size_t)l*GATES*HID;
  int tx = threadIdx.x, ty = threadIdx.y;
  #pragma unroll
  for (int i=0;i<4;i++)
    tile[ty+i*8][tx] = src[(size_t)(k0+ty+i*8)*GATES + n0 + tx];
  __syncthreads();
  #pragma unroll
  for (int i=0;i<4;i++)
    dst[(size_t)(n0+ty+i*8)*HID + k0 + tx] = tile[tx][ty+i*8];
}

// ---------- f32 GEMM: C[r] = Arow(r)·W + b1 (+ b2) ; K fixed = 1024 ----------
template<int AMODE, int OMODE>
__global__ __launch_bounds__(256) void k_gemm(
    const float* __restrict__ A,
    const float* __restrict__ W,     // [1024][N] row-major
    const float* __restrict__ b1,
    const float* __restrict__ b2,
    const int*   __restrict__ tokens,
    const float* __restrict__ emb,
    float* __restrict__ C, int N)
{
  __shared__ float As[16*132];   // transposed A tile [k][m], padded stride
  __shared__ float Bs[16*128];   // W tile [k][n]
  int tid = threadIdx.x;
  int m0 = blockIdx.y*128, n0 = blockIdx.x*128;

  int arow = tid >> 1;
  int akq  = (tid & 1) * 8;
  const float* aptr;
  { int gm = m0 + arow;
    if (AMODE==1){ int tt = gm>>3, bb = gm&7; aptr = emb + (size_t)tokens[bb*SEQ+tt]*1024; }
    else          aptr = A + (size_t)gm*1024; }

  int bk = tid >> 5;
  int bn = (tid & 31) * 4;
  const float* wptr = W + (size_t)bk*N + n0 + bn;

  int tx = tid & 15, ty = tid >> 4;
  float acc[8][8];
  #pragma unroll
  for (int i=0;i<8;i++){
    #pragma unroll
    for (int j=0;j<8;j++) acc[i][j] = 0.0f;
  }

  for (int k0=0;k0<1024;k0+=16){
    float4 av0 = *(const float4*)(aptr + k0 + akq);
    float4 av1 = *(const float4*)(aptr + k0 + akq + 4);
    float4 wv0 = *(const float4*)(wptr + (size_t)k0*N);
    float4 wv1 = *(const float4*)(wptr + (size_t)(k0+8)*N);
    __syncthreads();
    As[(akq+0)*132 + arow] = av0.x;
    As[(akq+1)*132 + arow] = av0.y;
    As[(akq+2)*132 + arow] = av0.z;
    As[(akq+3)*132 + arow] = av0.w;
    As[(akq+4)*132 + arow] = av1.x;
    As[(akq+5)*132 + arow] = av1.y;
    As[(akq+6)*132 + arow] = av1.z;
    As[(akq+7)*132 + arow] = av1.w;
    *(float4*)&Bs[bk*128 + bn]     = wv0;
    *(float4*)&Bs[(bk+8)*128 + bn] = wv1;
    __syncthreads();
    #pragma unroll
    for (int k=0;k<16;k++){
      float ra[8], rb[8];
      *(float4*)&ra[0] = *(float4*)&As[k*132 + ty*8];
      *(float4*)&ra[4] = *(float4*)&As[k*132 + ty*8 + 4];
      *(float4*)&rb[0] = *(float4*)&Bs[k*128 + tx*8];
      *(float4*)&rb[4] = *(float4*)&Bs[k*128 + tx*8 + 4];
      #pragma unroll
      for (int i=0;i<8;i++){
        #pragma unroll
        for (int j=0;j<8;j++)
          acc[i][j] = fmaf(ra[i], rb[j], acc[i][j]);
      }
    }
  }

  float bias[8];
  { int nb = n0 + tx*8;
    *(float4*)&bias[0] = *(const float4*)(b1 + nb);
    *(float4*)&bias[4] = *(const float4*)(b1 + nb + 4);
    if (b2){
      float4 c0 = *(const float4*)(b2 + nb);
      float4 c1 = *(const float4*)(b2 + nb + 4);
      bias[0]+=c0.x; bias[1]+=c0.y; bias[2]+=c0.z; bias[3]+=c0.w;
      bias[4]+=c1.x; bias[5]+=c1.y; bias[6]+=c1.z; bias[7]+=c1.w;
    }
  }
  #pragma unroll
  for (int i=0;i<8;i++){
    int gm = m0 + ty*8 + i;
    float* crow;
    if (OMODE==1) crow = C + ((size_t)(gm&7)*SEQ + (gm>>3))*N;
    else          crow = C + (size_t)gm*N;
    float4 o0, o1;
    o0.x = acc[i][0]+bias[0]; o0.y = acc[i][1]+bias[1];
    o0.z = acc[i][2]+bias[2]; o0.w = acc[i][3]+bias[3];
    o1.x = acc[i][4]+bias[4]; o1.y = acc[i][5]+bias[5];
    o1.z = acc[i][6]+bias[6]; o1.w = acc[i][7]+bias[7];
    *(float4*)(crow + n0 + tx*8)     = o0;
    *(float4*)(crow + n0 + tx*8 + 4) = o1;
  }
}

// ---------- persistent recurrence v5: relaxed-spin barrier, single fences ----------
// Transport identical to v3 (plain h stores/loads, proven correct); barrier:
//   arrival: grp ACQ_REL fetch_add (release: flushes this block's h stores;
//            leader acquires group), 32nd arriver RELEASE-bumps mst.
//   detect:  RELAXED spin on mst (no per-iteration cache maintenance; v4
//            showed relaxed loads observe fabric updates), then ONE acquire
//            fence. Fallback to acquire-spin after 100k iters (correctness).
__global__ __launch_bounds__(256) void k_rec(
    const float* __restrict__ G,
    const float* __restrict__ WhT,
    float* __restrict__ Hout,        // [2048][1024], row = t*8+b
    float* __restrict__ hb,          // ping-pong [2][8][1024]
    unsigned* __restrict__ grp,      // [256][8][16]
    unsigned* __restrict__ mst)      // [256][32]
{
  extern __shared__ float lds[];
  float* Wl  = lds;            // [16][1028]
  float* hl  = lds + 16448;    // [8][1028]
  float* gsc = lds + 24672;    // [4][64][2]
  int tid = threadIdx.x;
  int u0 = blockIdx.x*4;
  const int g = blockIdx.x & 7;

  // one-time: stage 16 gate columns (c = gate*4+unit) into LDS
  {
    int c = tid >> 4, ks = tid & 15;
    const float* src = WhT + ((size_t)(c>>2)*1024 + u0 + (c&3))*1024 + ks*64;
    float* dst = Wl + c*1028 + ks*64;
    #pragma unroll
    for (int i=0;i<16;i++)
      *(float4*)(dst + i*4) = *(const float4*)(src + i*4);
  }

  const int wv = tid >> 6, ln = tid & 63;
  const int db = ln >> 3, dc = ln & 7;         // dot roles: batch, col (and col+8)
  const int kbase = wv*256;
  const int sb = tid & 7, sk = (tid >> 3)*32;  // h-staging roles
  const int cb = tid >> 2, cj = tid & 3;       // cell roles (tid<32)
  float creg = 0.0f;

  for (int t=0;t<SEQ;t++){
    const float* hcur = hb + (t&1)*8192;
    // stage h[8][1024] -> hl
    {
      const float* src = hcur + sb*1024 + sk;
      float* dst = hl + sb*1028 + sk;
      #pragma unroll
      for (int i=0;i<8;i++)
        *(float4*)(dst + i*4) = *(const float4*)(src + i*4);
    }
    // prefetch x-gate pre-activations (consumed after dot loop)
    float gp0=0.f,gp1=0.f,gp2=0.f,gp3=0.f;
    if (tid < 32){
      const float* gp = G + ((size_t)t*8 + cb)*GATES + u0 + cj;
      gp0 = gp[0]; gp1 = gp[1024]; gp2 = gp[2048]; gp3 = gp[3072];
    }
    __syncthreads();

    // dot: cols dc and dc+8 for batch db over K [kbase, kbase+256)
    float a0 = 0.f, a1 = 0.f;
    const float* hp = hl + db*1028 + kbase;
    const float* w0 = Wl + dc*1028 + kbase;
    const float* w1 = Wl + (dc+8)*1028 + kbase;
    #pragma unroll 4
    for (int k=0;k<256;k+=4){
      float4 hv = *(const float4*)(hp + k);
      float4 x0 = *(const float4*)(w0 + k);
      float4 x1 = *(const float4*)(w1 + k);
      a0 = fmaf(hv.x,x0.x,a0); a0 = fmaf(hv.y,x0.y,a0);
      a0 = fmaf(hv.z,x0.z,a0); a0 = fmaf(hv.w,x0.w,a0);
      a1 = fmaf(hv.x,x1.x,a1); a1 = fmaf(hv.y,x1.y,a1);
      a1 = fmaf(hv.z,x1.z,a1); a1 = fmaf(hv.w,x1.w,a1);
    }
    gsc[wv*128 + ln*2 + 0] = a0;
    gsc[wv*128 + ln*2 + 1] = a1;
    __syncthreads();

    // cell update: thread (cb, cj) owns (batch cb, unit u0+cj); reduce inline
    if (tid < 32){
      int b0 = (cb*8 + cj)*2, b1i = (cb*8 + 4 + cj)*2;
      float xi = gp0, xf = gp1, xg = gp2, xo = gp3;
      #pragma unroll
      for (int w=0;w<4;w++){
        xi += gsc[w*128 + b0];
        xf += gsc[w*128 + b1i];
        xg += gsc[w*128 + b0 + 1];
        xo += gsc[w*128 + b1i + 1];
      }
      float iv = sigf(xi), fv = sigf(xf), ov = sigf(xo), gv = tanhf_(xg);
      creg = fv*creg + iv*gv;
      float hv = ov * tanhf_(creg);
      hb[((t+1)&1)*8192 + cb*1024 + u0 + cj] = hv;
      Hout[((size_t)t*8 + cb)*HID + u0 + cj] = hv;
    }

    // grid barrier for phase t: release arrival, relaxed spin, one acquire fence
    if (tid == 0){
      unsigned old = __hip_atomic_fetch_add(&grp[(t*8+g)*16], 1u,
                        __ATOMIC_ACQ_REL, __HIP_MEMORY_SCOPE_AGENT);
      if (old == 31u)
        __hip_atomic_fetch_add(&mst[t*32], 1u,
                        __ATOMIC_RELEASE, __HIP_MEMORY_SCOPE_AGENT);
      int spins = 0;
      while (__hip_atomic_load(&mst[t*32], __ATOMIC_RELAXED,
                               __HIP_MEMORY_SCOPE_AGENT) < 8u){
        __builtin_amdgcn_s_sleep(2);
        if (++spins > 100000){
          // fallback: acquire-spin (per-iter invalidate, guaranteed fresh)
          while (__hip_atomic_load(&mst[t*32], __ATOMIC_ACQUIRE,
                                   __HIP_MEMORY_SCOPE_AGENT) < 8u){
            __builtin_amdgcn_s_sleep(8);
            if (++spins > 8000000) break;  // wrong answer beats a hang
          }
          break;
        }
      }
      __builtin_amdgcn_fence(__ATOMIC_ACQUIRE, "agent");
    }
    __syncthreads();
  }
}

extern "C" void kernel_launch(void* const* d_in, const int* in_sizes, int n_in,
                              void* d_out, int out_size, void* d_ws, size_t ws_size,
                              hipStream_t stream) {
  const int*   tokens = (const int*)d_in[0];
  const float* emb = (const float*)d_in[1];
  const float* Wx  = (const float*)d_in[2];
  const float* bx  = (const float*)d_in[3];
  const float* Wh  = (const float*)d_in[4];
  const float* bh  = (const float*)d_in[5];
  const float* Wd  = (const float*)d_in[6];
  const float* bd  = (const float*)d_in[7];
  float* out = (float*)d_out;
  float* ws  = (float*)d_ws;

  // ws layout (floats): G 8388608 | H0 2097152 | Tops 2097152 | WhT 8388608 |
  //                     hb 32768 | grp 65536 (2x256x8x16) | mst 16384 (2x256x32)
  float* G    = ws;
  float* H0   = ws + (size_t)8388608;
  float* Tops = ws + (size_t)10485760;
  float* WhT  = ws + (size_t)12582912;
  float* hb   = ws + (size_t)20971520;
  unsigned* grp = (unsigned*)(ws + (size_t)21004288);
  unsigned* mst = (unsigned*)(ws + (size_t)21069824);

  (void)hipFuncSetAttribute((const void*)k_rec,
        hipFuncAttributeMaxDynamicSharedMemorySize, 101376);

  k_init<<<32,256,0,stream>>>(grp, mst, hb);
  k_transpose<<<dim3(128,32,2), dim3(32,8), 0, stream>>>(Wh, WhT);

  // layer 0: G0 = emb[tok] @ Wx0 + (bx0+bh0)
  k_gemm<1,0><<<dim3(32,16),256,0,stream>>>(nullptr, Wx, bx, bh, tokens, emb, G, GATES);
  k_rec<<<256,256,101376,stream>>>(G, WhT, H0, hb, grp, mst);

  // layer 1: G1 = H0 @ Wx1 + (bx1+bh1)
  k_gemm<0,0><<<dim3(32,16),256,0,stream>>>(H0, Wx + (size_t)1024*GATES, bx+GATES, bh+GATES,
                                            nullptr, nullptr, G, GATES);
  k_rec<<<256,256,101376,stream>>>(G, WhT + (size_t)GATES*HID, Tops, hb + 2*BATCH*HID,
                                  grp + 256*8*16, mst + 256*32);

  // final projection: out[b][t][v] = Tops[t*8+b] @ Wd + bd
  k_gemm<0,1><<<dim3(250,16),256,0,stream>>>(Tops, Wd, bd, nullptr, nullptr, nullptr, out, VOC);
}

// Round 6
// 7998.002 us; speedup vs baseline: 2.3133x; 1.0907x over previous
//
#include <hip/hip_runtime.h>
#include <cstdint>
#include <cstddef>

#define BATCH 8
#define SEQ   256
#define HID   1024
#define GATES 4096   // 4*HID
#define VOC   32000

// ---------- helpers ----------
__device__ __forceinline__ float sigf(float x){ return 1.0f/(1.0f + __expf(-x)); }
__device__ __forceinline__ float tanhf_(float x){ return 1.0f - 2.0f/(__expf(2.0f*x) + 1.0f); }

// ---------- init: zero epoch flags + h ping-pong buffers ----------
// flags: 2 layers x [256][16] uints (64B slots). hb: 2 layers x [2][8][1024].
__global__ void k_init(unsigned* __restrict__ flags, float* __restrict__ hb){
  int tid = blockIdx.x*blockDim.x + threadIdx.x;
  int nt = gridDim.x*blockDim.x;
  for (int i = tid; i < 2*256*16; i += nt) flags[i] = 0u;
  for (int i = tid; i < 2*2*BATCH*HID; i += nt) hb[i] = 0.0f;
}

// ---------- Wh transpose: WhT[l][n][k] = Wh[l][k][n] ----------
__global__ void k_transpose(const float* __restrict__ Wh, float* __restrict__ WhT){
  __shared__ float tile[32][33];
  int l = blockIdx.z;
  int n0 = blockIdx.x*32, k0 = blockIdx.y*32;
  const float* src = Wh  + (size_t)l*HID*GATES;
  float*       dst = WhT + (size_t)l*GATES*HID;
  int tx = threadIdx.x, ty = threadIdx.y;
  #pragma unroll
  for (int i=0;i<4;i++)
    tile[ty+i*8][tx] = src[(size_t)(k0+ty+i*8)*GATES + n0 + tx];
  __syncthreads();
  #pragma unroll
  for (int i=0;i<4;i++)
    dst[(size_t)(n0+ty+i*8)*HID + k0 + tx] = tile[tx][ty+i*8];
}

// ---------- f32 GEMM: C[r] = Arow(r)·W + b1 (+ b2) ; K fixed = 1024 ----------
template<int AMODE, int OMODE>
__global__ __launch_bounds__(256) void k_gemm(
    const float* __restrict__ A,
    const float* __restrict__ W,     // [1024][N] row-major
    const float* __restrict__ b1,
    const float* __restrict__ b2,
    const int*   __restrict__ tokens,
    const float* __restrict__ emb,
    float* __restrict__ C, int N)
{
  __shared__ float As[16*132];   // transposed A tile [k][m], padded stride
  __shared__ float Bs[16*128];   // W tile [k][n]
  int tid = threadIdx.x;
  int m0 = blockIdx.y*128, n0 = blockIdx.x*128;

  int arow = tid >> 1;
  int akq  = (tid & 1) * 8;
  const float* aptr;
  { int gm = m0 + arow;
    if (AMODE==1){ int tt = gm>>3, bb = gm&7; aptr = emb + (size_t)tokens[bb*SEQ+tt]*1024; }
    else          aptr = A + (size_t)gm*1024; }

  int bk = tid >> 5;
  int bn = (tid & 31) * 4;
  const float* wptr = W + (size_t)bk*N + n0 + bn;

  int tx = tid & 15, ty = tid >> 4;
  float acc[8][8];
  #pragma unroll
  for (int i=0;i<8;i++){
    #pragma unroll
    for (int j=0;j<8;j++) acc[i][j] = 0.0f;
  }

  for (int k0=0;k0<1024;k0+=16){
    float4 av0 = *(const float4*)(aptr + k0 + akq);
    float4 av1 = *(const float4*)(aptr + k0 + akq + 4);
    float4 wv0 = *(const float4*)(wptr + (size_t)k0*N);
    float4 wv1 = *(const float4*)(wptr + (size_t)(k0+8)*N);
    __syncthreads();
    As[(akq+0)*132 + arow] = av0.x;
    As[(akq+1)*132 + arow] = av0.y;
    As[(akq+2)*132 + arow] = av0.z;
    As[(akq+3)*132 + arow] = av0.w;
    As[(akq+4)*132 + arow] = av1.x;
    As[(akq+5)*132 + arow] = av1.y;
    As[(akq+6)*132 + arow] = av1.z;
    As[(akq+7)*132 + arow] = av1.w;
    *(float4*)&Bs[bk*128 + bn]     = wv0;
    *(float4*)&Bs[(bk+8)*128 + bn] = wv1;
    __syncthreads();
    #pragma unroll
    for (int k=0;k<16;k++){
      float ra[8], rb[8];
      *(float4*)&ra[0] = *(float4*)&As[k*132 + ty*8];
      *(float4*)&ra[4] = *(float4*)&As[k*132 + ty*8 + 4];
      *(float4*)&rb[0] = *(float4*)&Bs[k*128 + tx*8];
      *(float4*)&rb[4] = *(float4*)&Bs[k*128 + tx*8 + 4];
      #pragma unroll
      for (int i=0;i<8;i++){
        #pragma unroll
        for (int j=0;j<8;j++)
          acc[i][j] = fmaf(ra[i], rb[j], acc[i][j]);
      }
    }
  }

  float bias[8];
  { int nb = n0 + tx*8;
    *(float4*)&bias[0] = *(const float4*)(b1 + nb);
    *(float4*)&bias[4] = *(const float4*)(b1 + nb + 4);
    if (b2){
      float4 c0 = *(const float4*)(b2 + nb);
      float4 c1 = *(const float4*)(b2 + nb + 4);
      bias[0]+=c0.x; bias[1]+=c0.y; bias[2]+=c0.z; bias[3]+=c0.w;
      bias[4]+=c1.x; bias[5]+=c1.y; bias[6]+=c1.z; bias[7]+=c1.w;
    }
  }
  #pragma unroll
  for (int i=0;i<8;i++){
    int gm = m0 + ty*8 + i;
    float* crow;
    if (OMODE==1) crow = C + ((size_t)(gm&7)*SEQ + (gm>>3))*N;
    else          crow = C + (size_t)gm*N;
    float4 o0, o1;
    o0.x = acc[i][0]+bias[0]; o0.y = acc[i][1]+bias[1];
    o0.z = acc[i][2]+bias[2]; o0.w = acc[i][3]+bias[3];
    o1.x = acc[i][4]+bias[4]; o1.y = acc[i][5]+bias[5];
    o1.z = acc[i][6]+bias[6]; o1.w = acc[i][7]+bias[7];
    *(float4*)(crow + n0 + tx*8)     = o0;
    *(float4*)(crow + n0 + tx*8 + 4) = o1;
  }
}

// ---------- persistent recurrence v6: release-store epoch-flag barrier ----------
// Arrival: tid0 executes fence(release,agent) [waitcnt + wbL2: publishes this
// block's h stores, all issued by the same wave] then a RELAXED store of epoch
// t+1 to its own 64B flag slot. Arrivals hit 256 distinct lines -> parallel.
// Detect: wave 0 relaxed-polls all 256 flags (4 slots/lane), then ONE acquire
// fence (inv) for the whole block. Fallback to acquire-loads after 150k spins.
__global__ __launch_bounds__(256) void k_rec(
    const float* __restrict__ G,
    const float* __restrict__ WhT,
    float* __restrict__ Hout,        // [2048][1024], row = t*8+b
    float* __restrict__ hb,          // ping-pong [2][8][1024]
    unsigned* __restrict__ flags)    // [256][16] epoch slots
{
  extern __shared__ float lds[];
  float* Wl  = lds;            // [16][1028]
  float* hl  = lds + 16448;    // [8][1028]
  float* gsc = lds + 24672;    // [4][64][2]
  int tid = threadIdx.x;
  int u0 = blockIdx.x*4;

  // one-time: stage 16 gate columns (c = gate*4+unit) into LDS
  {
    int c = tid >> 4, ks = tid & 15;
    const float* src = WhT + ((size_t)(c>>2)*1024 + u0 + (c&3))*1024 + ks*64;
    float* dst = Wl + c*1028 + ks*64;
    #pragma unroll
    for (int i=0;i<16;i++)
      *(float4*)(dst + i*4) = *(const float4*)(src + i*4);
  }

  const int wv = tid >> 6, ln = tid & 63;
  const int db = ln >> 3, dc = ln & 7;         // dot roles: batch, col (and col+8)
  const int kbase = wv*256;
  const int sb = tid & 7, sk = (tid >> 3)*32;  // h-staging roles
  const int cb = tid >> 2, cj = tid & 3;       // cell roles (tid<32)
  const int fs0 = tid*16, fs1 = (tid+64)*16, fs2 = (tid+128)*16, fs3 = (tid+192)*16;
  float creg = 0.0f;

  for (int t=0;t<SEQ;t++){
    const float* hcur = hb + (t&1)*8192;
    // stage h[8][1024] -> hl
    {
      const float* src = hcur + sb*1024 + sk;
      float* dst = hl + sb*1028 + sk;
      #pragma unroll
      for (int i=0;i<8;i++)
        *(float4*)(dst + i*4) = *(const float4*)(src + i*4);
    }
    // prefetch x-gate pre-activations (consumed after dot loop)
    float gp0=0.f,gp1=0.f,gp2=0.f,gp3=0.f;
    if (tid < 32){
      const float* gp = G + ((size_t)t*8 + cb)*GATES + u0 + cj;
      gp0 = gp[0]; gp1 = gp[1024]; gp2 = gp[2048]; gp3 = gp[3072];
    }
    __syncthreads();

    // dot: cols dc and dc+8 for batch db over K [kbase, kbase+256)
    float a0 = 0.f, a1 = 0.f;
    const float* hp = hl + db*1028 + kbase;
    const float* w0 = Wl + dc*1028 + kbase;
    const float* w1 = Wl + (dc+8)*1028 + kbase;
    #pragma unroll 4
    for (int k=0;k<256;k+=4){
      float4 hv = *(const float4*)(hp + k);
      float4 x0 = *(const float4*)(w0 + k);
      float4 x1 = *(const float4*)(w1 + k);
      a0 = fmaf(hv.x,x0.x,a0); a0 = fmaf(hv.y,x0.y,a0);
      a0 = fmaf(hv.z,x0.z,a0); a0 = fmaf(hv.w,x0.w,a0);
      a1 = fmaf(hv.x,x1.x,a1); a1 = fmaf(hv.y,x1.y,a1);
      a1 = fmaf(hv.z,x1.z,a1); a1 = fmaf(hv.w,x1.w,a1);
    }
    gsc[wv*128 + ln*2 + 0] = a0;
    gsc[wv*128 + ln*2 + 1] = a1;
    __syncthreads();

    // cell update: thread (cb, cj) owns (batch cb, unit u0+cj); reduce inline
    if (tid < 32){
      int b0 = (cb*8 + cj)*2, b1i = (cb*8 + 4 + cj)*2;
      float xi = gp0, xf = gp1, xg = gp2, xo = gp3;
      #pragma unroll
      for (int w=0;w<4;w++){
        xi += gsc[w*128 + b0];
        xf += gsc[w*128 + b1i];
        xg += gsc[w*128 + b0 + 1];
        xo += gsc[w*128 + b1i + 1];
      }
      float iv = sigf(xi), fv = sigf(xf), ov = sigf(xo), gv = tanhf_(xg);
      creg = fv*creg + iv*gv;
      float hv = ov * tanhf_(creg);
      hb[((t+1)&1)*8192 + cb*1024 + u0 + cj] = hv;
      Hout[((size_t)t*8 + cb)*HID + u0 + cj] = hv;
    }

    // epoch-flag grid barrier (skip after last step: kernel-end release covers Hout)
    if (t < SEQ-1){
      if (tid < 64){
        if (tid == 0){
          __builtin_amdgcn_fence(__ATOMIC_RELEASE, "agent");   // waitcnt + wbL2
          __hip_atomic_store(&flags[blockIdx.x*16], (unsigned)(t+1),
                             __ATOMIC_RELAXED, __HIP_MEMORY_SCOPE_AGENT);
        }
        unsigned tgt = (unsigned)(t+1);
        int spins = 0;
        for (;;){
          unsigned a = __hip_atomic_load(&flags[fs0], __ATOMIC_RELAXED, __HIP_MEMORY_SCOPE_AGENT);
          unsigned b = __hip_atomic_load(&flags[fs1], __ATOMIC_RELAXED, __HIP_MEMORY_SCOPE_AGENT);
          unsigned c = __hip_atomic_load(&flags[fs2], __ATOMIC_RELAXED, __HIP_MEMORY_SCOPE_AGENT);
          unsigned d = __hip_atomic_load(&flags[fs3], __ATOMIC_RELAXED, __HIP_MEMORY_SCOPE_AGENT);
          bool ok = (a >= tgt) && (b >= tgt) && (c >= tgt) && (d >= tgt);
          if (__all(ok)) break;
          __builtin_amdgcn_s_sleep(1);
          if (++spins > 150000){
            // fallback: acquire-loads (per-iter invalidate, guaranteed fresh)
            for (;;){
              unsigned a2 = __hip_atomic_load(&flags[fs0], __ATOMIC_ACQUIRE, __HIP_MEMORY_SCOPE_AGENT);
              unsigned b2 = __hip_atomic_load(&flags[fs1], __ATOMIC_ACQUIRE, __HIP_MEMORY_SCOPE_AGENT);
              unsigned c2 = __hip_atomic_load(&flags[fs2], __ATOMIC_ACQUIRE, __HIP_MEMORY_SCOPE_AGENT);
              unsigned d2 = __hip_atomic_load(&flags[fs3], __ATOMIC_ACQUIRE, __HIP_MEMORY_SCOPE_AGENT);
              bool ok2 = (a2 >= tgt) && (b2 >= tgt) && (c2 >= tgt) && (d2 >= tgt);
              if (__all(ok2)) break;
              __builtin_amdgcn_s_sleep(8);
              if (++spins > 8000000) break;  // wrong answer beats a hang
            }
            break;
          }
        }
        __builtin_amdgcn_fence(__ATOMIC_ACQUIRE, "agent");     // one inv for the block
      }
      __syncthreads();
    }
  }
}

extern "C" void kernel_launch(void* const* d_in, const int* in_sizes, int n_in,
                              void* d_out, int out_size, void* d_ws, size_t ws_size,
                              hipStream_t stream) {
  const int*   tokens = (const int*)d_in[0];
  const float* emb = (const float*)d_in[1];
  const float* Wx  = (const float*)d_in[2];
  const float* bx  = (const float*)d_in[3];
  const float* Wh  = (const float*)d_in[4];
  const float* bh  = (const float*)d_in[5];
  const float* Wd  = (const float*)d_in[6];
  const float* bd  = (const float*)d_in[7];
  float* out = (float*)d_out;
  float* ws  = (float*)d_ws;

  // ws layout (floats): G 8388608 | H0 2097152 | Tops 2097152 | WhT 8388608 |
  //                     hb 32768 (2 layers x 2 x 8192) | flags 8192 (2 x 4096)
  float* G    = ws;
  float* H0   = ws + (size_t)8388608;
  float* Tops = ws + (size_t)10485760;
  float* WhT  = ws + (size_t)12582912;
  float* hb   = ws + (size_t)20971520;
  unsigned* flags = (unsigned*)(ws + (size_t)21004288);

  (void)hipFuncSetAttribute((const void*)k_rec,
        hipFuncAttributeMaxDynamicSharedMemorySize, 101376);

  k_init<<<32,256,0,stream>>>(flags, hb);
  k_transpose<<<dim3(128,32,2), dim3(32,8), 0, stream>>>(Wh, WhT);

  // layer 0: G0 = emb[tok] @ Wx0 + (bx0+bh0)
  k_gemm<1,0><<<dim3(32,16),256,0,stream>>>(nullptr, Wx, bx, bh, tokens, emb, G, GATES);
  k_rec<<<256,256,101376,stream>>>(G, WhT, H0, hb, flags);

  // layer 1: G1 = H0 @ Wx1 + (bx1+bh1)
  k_gemm<0,0><<<dim3(32,16),256,0,stream>>>(H0, Wx + (size_t)1024*GATES, bx+GATES, bh+GATES,
                                            nullptr, nullptr, G, GATES);
  k_rec<<<256,256,101376,stream>>>(G, WhT + (size_t)GATES*HID, Tops, hb + 2*BATCH*HID,
                                   flags + 4096);

  // final projection: out[b][t][v] = Tops[t*8+b] @ Wd + bd
  k_gemm<0,1><<<dim3(250,16),256,0,stream>>>(Tops, Wd, bd, nullptr, nullptr, nullptr, out, VOC);
}

// Round 7
// 5915.186 us; speedup vs baseline: 3.1279x; 1.3521x over previous
//
#include <hip/hip_runtime.h>
#include <cstdint>
#include <cstddef>

#define BATCH 8
#define SEQ   256
#define HID   1024
#define GATES 4096   // 4*HID
#define VOC   32000

// ---------- helpers ----------
__device__ __forceinline__ float sigf(float x){ return 1.0f/(1.0f + __expf(-x)); }
__device__ __forceinline__ float tanhf_(float x){ return 1.0f - 2.0f/(__expf(2.0f*x) + 1.0f); }

// ---------- init: zero epoch flags + h ping-pong buffers ----------
// flags: 2 layers x [256][16] uints (64B slots). hb: 2 layers x [2][8][1024].
__global__ void k_init(unsigned* __restrict__ flags, float* __restrict__ hb){
  int tid = blockIdx.x*blockDim.x + threadIdx.x;
  int nt = gridDim.x*blockDim.x;
  for (int i = tid; i < 2*256*16; i += nt) flags[i] = 0u;
  for (int i = tid; i < 2*2*BATCH*HID; i += nt) hb[i] = 0.0f;
}

// ---------- Wh transpose: WhT[l][n][k] = Wh[l][k][n] ----------
__global__ void k_transpose(const float* __restrict__ Wh, float* __restrict__ WhT){
  __shared__ float tile[32][33];
  int l = blockIdx.z;
  int n0 = blockIdx.x*32, k0 = blockIdx.y*32;
  const float* src = Wh  + (size_t)l*HID*GATES;
  float*       dst = WhT + (size_t)l*GATES*HID;
  int tx = threadIdx.x, ty = threadIdx.y;
  #pragma unroll
  for (int i=0;i<4;i++)
    tile[ty+i*8][tx] = src[(size_t)(k0+ty+i*8)*GATES + n0 + tx];
  __syncthreads();
  #pragma unroll
  for (int i=0;i<4;i++)
    dst[(size_t)(n0+ty+i*8)*HID + k0 + tx] = tile[tx][ty+i*8];
}

// ---------- f32 GEMM: C[r] = Arow(r)·W + b1 (+ b2) ; K fixed = 1024 ----------
template<int AMODE, int OMODE>
__global__ __launch_bounds__(256) void k_gemm(
    const float* __restrict__ A,
    const float* __restrict__ W,     // [1024][N] row-major
    const float* __restrict__ b1,
    const float* __restrict__ b2,
    const int*   __restrict__ tokens,
    const float* __restrict__ emb,
    float* __restrict__ C, int N)
{
  __shared__ float As[16*132];   // transposed A tile [k][m], padded stride
  __shared__ float Bs[16*128];   // W tile [k][n]
  int tid = threadIdx.x;
  int m0 = blockIdx.y*128, n0 = blockIdx.x*128;

  int arow = tid >> 1;
  int akq  = (tid & 1) * 8;
  const float* aptr;
  { int gm = m0 + arow;
    if (AMODE==1){ int tt = gm>>3, bb = gm&7; aptr = emb + (size_t)tokens[bb*SEQ+tt]*1024; }
    else          aptr = A + (size_t)gm*1024; }

  int bk = tid >> 5;
  int bn = (tid & 31) * 4;
  const float* wptr = W + (size_t)bk*N + n0 + bn;

  int tx = tid & 15, ty = tid >> 4;
  float acc[8][8];
  #pragma unroll
  for (int i=0;i<8;i++){
    #pragma unroll
    for (int j=0;j<8;j++) acc[i][j] = 0.0f;
  }

  for (int k0=0;k0<1024;k0+=16){
    float4 av0 = *(const float4*)(aptr + k0 + akq);
    float4 av1 = *(const float4*)(aptr + k0 + akq + 4);
    float4 wv0 = *(const float4*)(wptr + (size_t)k0*N);
    float4 wv1 = *(const float4*)(wptr + (size_t)(k0+8)*N);
    __syncthreads();
    As[(akq+0)*132 + arow] = av0.x;
    As[(akq+1)*132 + arow] = av0.y;
    As[(akq+2)*132 + arow] = av0.z;
    As[(akq+3)*132 + arow] = av0.w;
    As[(akq+4)*132 + arow] = av1.x;
    As[(akq+5)*132 + arow] = av1.y;
    As[(akq+6)*132 + arow] = av1.z;
    As[(akq+7)*132 + arow] = av1.w;
    *(float4*)&Bs[bk*128 + bn]     = wv0;
    *(float4*)&Bs[(bk+8)*128 + bn] = wv1;
    __syncthreads();
    #pragma unroll
    for (int k=0;k<16;k++){
      float ra[8], rb[8];
      *(float4*)&ra[0] = *(float4*)&As[k*132 + ty*8];
      *(float4*)&ra[4] = *(float4*)&As[k*132 + ty*8 + 4];
      *(float4*)&rb[0] = *(float4*)&Bs[k*128 + tx*8];
      *(float4*)&rb[4] = *(float4*)&Bs[k*128 + tx*8 + 4];
      #pragma unroll
      for (int i=0;i<8;i++){
        #pragma unroll
        for (int j=0;j<8;j++)
          acc[i][j] = fmaf(ra[i], rb[j], acc[i][j]);
      }
    }
  }

  float bias[8];
  { int nb = n0 + tx*8;
    *(float4*)&bias[0] = *(const float4*)(b1 + nb);
    *(float4*)&bias[4] = *(const float4*)(b1 + nb + 4);
    if (b2){
      float4 c0 = *(const float4*)(b2 + nb);
      float4 c1 = *(const float4*)(b2 + nb + 4);
      bias[0]+=c0.x; bias[1]+=c0.y; bias[2]+=c0.z; bias[3]+=c0.w;
      bias[4]+=c1.x; bias[5]+=c1.y; bias[6]+=c1.z; bias[7]+=c1.w;
    }
  }
  #pragma unroll
  for (int i=0;i<8;i++){
    int gm = m0 + ty*8 + i;
    float* crow;
    if (OMODE==1) crow = C + ((size_t)(gm&7)*SEQ + (gm>>3))*N;
    else          crow = C + (size_t)gm*N;
    float4 o0, o1;
    o0.x = acc[i][0]+bias[0]; o0.y = acc[i][1]+bias[1];
    o0.z = acc[i][2]+bias[2]; o0.w = acc[i][3]+bias[3];
    o1.x = acc[i][4]+bias[4]; o1.y = acc[i][5]+bias[5];
    o1.z = acc[i][6]+bias[6]; o1.w = acc[i][7]+bias[7];
    *(float4*)(crow + n0 + tx*8)     = o0;
    *(float4*)(crow + n0 + tx*8 + 4) = o1;
  }
}

// ---------- persistent recurrence v7: fence-free MALL message-passing ----------
// Publish: cell threads (wave 0) write h via RELAXED atomic_exchange (RMWs
// execute AT the coherence point; vmcnt-ack => MALL-visible), then tid0 does
// s_waitcnt vmcnt(0) and a relaxed flag exchange. Flag visible => h visible.
// Detect: wave 0 relaxed-polls 256 flags; NO acquire fence.
// Stage: h read with global_load_dwordx4 sc0 sc1 (bypass L1+L2, read MALL).
// Zero cache-maintenance ops in the loop -> G/Wl stay cached.
__global__ __launch_bounds__(256) void k_rec(
    const float* __restrict__ G,
    const float* __restrict__ WhT,
    float* __restrict__ Hout,        // [2048][1024], row = t*8+b
    unsigned* __restrict__ hb,       // ping-pong [2][8][1024] as uint bits
    unsigned* __restrict__ flags)    // [256][16] epoch slots
{
  extern __shared__ float lds[];
  float* Wl  = lds;            // [16][1028]
  float* hl  = lds + 16448;    // [8][1028]
  float* gsc = lds + 24672;    // [4][64][2]
  int tid = threadIdx.x;
  int u0 = blockIdx.x*4;

  // one-time: stage 16 gate columns (c = gate*4+unit) into LDS
  {
    int c = tid >> 4, ks = tid & 15;
    const float* src = WhT + ((size_t)(c>>2)*1024 + u0 + (c&3))*1024 + ks*64;
    float* dst = Wl + c*1028 + ks*64;
    #pragma unroll
    for (int i=0;i<16;i++)
      *(float4*)(dst + i*4) = *(const float4*)(src + i*4);
  }

  const int wv = tid >> 6, ln = tid & 63;
  const int db = ln >> 3, dc = ln & 7;         // dot roles: batch, col (and col+8)
  const int kbase = wv*256;
  const int sb = tid & 7, sk = (tid >> 3)*32;  // h-staging roles
  const int cb = tid >> 2, cj = tid & 3;       // cell roles (tid<32)
  const int fs0 = tid*16, fs1 = (tid+64)*16, fs2 = (tid+128)*16, fs3 = (tid+192)*16;
  float creg = 0.0f;

  for (int t=0;t<SEQ;t++){
    // stage h[8][1024] -> hl: 32 consecutive floats/thread via L1/L2-bypass loads
    {
      const float* src = (const float*)(hb + (t&1)*8192) + sb*1024 + sk;
      float4 r0,r1,r2,r3,r4,r5,r6,r7;
      asm volatile(
        "global_load_dwordx4 %0, %8, off sc0 sc1\n\t"
        "global_load_dwordx4 %1, %8, off offset:16 sc0 sc1\n\t"
        "global_load_dwordx4 %2, %8, off offset:32 sc0 sc1\n\t"
        "global_load_dwordx4 %3, %8, off offset:48 sc0 sc1\n\t"
        "global_load_dwordx4 %4, %8, off offset:64 sc0 sc1\n\t"
        "global_load_dwordx4 %5, %8, off offset:80 sc0 sc1\n\t"
        "global_load_dwordx4 %6, %8, off offset:96 sc0 sc1\n\t"
        "global_load_dwordx4 %7, %8, off offset:112 sc0 sc1\n\t"
        "s_waitcnt vmcnt(0)"
        : "=&v"(r0),"=&v"(r1),"=&v"(r2),"=&v"(r3),
          "=&v"(r4),"=&v"(r5),"=&v"(r6),"=&v"(r7)
        : "v"(src)
        : "memory");
      float* dst = hl + sb*1028 + sk;
      *(float4*)(dst+ 0)=r0; *(float4*)(dst+ 4)=r1;
      *(float4*)(dst+ 8)=r2; *(float4*)(dst+12)=r3;
      *(float4*)(dst+16)=r4; *(float4*)(dst+20)=r5;
      *(float4*)(dst+24)=r6; *(float4*)(dst+28)=r7;
    }
    // prefetch x-gate pre-activations (plain cached loads; G is read-only)
    float gp0=0.f,gp1=0.f,gp2=0.f,gp3=0.f;
    if (tid < 32){
      const float* gp = G + ((size_t)t*8 + cb)*GATES + u0 + cj;
      gp0 = gp[0]; gp1 = gp[1024]; gp2 = gp[2048]; gp3 = gp[3072];
    }
    __syncthreads();

    // dot: cols dc and dc+8 for batch db over K [kbase, kbase+256)
    float a0 = 0.f, a1 = 0.f;
    const float* hp = hl + db*1028 + kbase;
    const float* w0 = Wl + dc*1028 + kbase;
    const float* w1 = Wl + (dc+8)*1028 + kbase;
    #pragma unroll 4
    for (int k=0;k<256;k+=4){
      float4 hv = *(const float4*)(hp + k);
      float4 x0 = *(const float4*)(w0 + k);
      float4 x1 = *(const float4*)(w1 + k);
      a0 = fmaf(hv.x,x0.x,a0); a0 = fmaf(hv.y,x0.y,a0);
      a0 = fmaf(hv.z,x0.z,a0); a0 = fmaf(hv.w,x0.w,a0);
      a1 = fmaf(hv.x,x1.x,a1); a1 = fmaf(hv.y,x1.y,a1);
      a1 = fmaf(hv.z,x1.z,a1); a1 = fmaf(hv.w,x1.w,a1);
    }
    gsc[wv*128 + ln*2 + 0] = a0;
    gsc[wv*128 + ln*2 + 1] = a1;
    __syncthreads();

    // cell update: thread (cb, cj) owns (batch cb, unit u0+cj); reduce inline
    if (tid < 32){
      int b0 = (cb*8 + cj)*2, b1i = (cb*8 + 4 + cj)*2;
      float xi = gp0, xf = gp1, xg = gp2, xo = gp3;
      #pragma unroll
      for (int w=0;w<4;w++){
        xi += gsc[w*128 + b0];
        xf += gsc[w*128 + b1i];
        xg += gsc[w*128 + b0 + 1];
        xo += gsc[w*128 + b1i + 1];
      }
      float iv = sigf(xi), fv = sigf(xf), ov = sigf(xo), gv = tanhf_(xg);
      creg = fv*creg + iv*gv;
      float hv = ov * tanhf_(creg);
      if (t < SEQ-1){
        // RMW publish: executes at MALL; vmcnt-ack == globally visible
        (void)__hip_atomic_exchange(&hb[((t+1)&1)*8192 + cb*1024 + u0 + cj],
                                    __float_as_uint(hv), __ATOMIC_RELAXED,
                                    __HIP_MEMORY_SCOPE_AGENT);
      }
      Hout[((size_t)t*8 + cb)*HID + u0 + cj] = hv;
    }

    // fence-free epoch barrier (skip after last step)
    if (t < SEQ-1){
      if (tid < 64){
        if (tid == 0){
          asm volatile("s_waitcnt vmcnt(0)" ::: "memory");  // wave-0 swaps done at MALL
          (void)__hip_atomic_exchange(&flags[blockIdx.x*16], (unsigned)(t+1),
                                      __ATOMIC_RELAXED, __HIP_MEMORY_SCOPE_AGENT);
        }
        unsigned tgt = (unsigned)(t+1);
        int spins = 0;
        for (;;){
          unsigned a = __hip_atomic_load(&flags[fs0], __ATOMIC_RELAXED, __HIP_MEMORY_SCOPE_AGENT);
          unsigned b = __hip_atomic_load(&flags[fs1], __ATOMIC_RELAXED, __HIP_MEMORY_SCOPE_AGENT);
          unsigned c = __hip_atomic_load(&flags[fs2], __ATOMIC_RELAXED, __HIP_MEMORY_SCOPE_AGENT);
          unsigned d = __hip_atomic_load(&flags[fs3], __ATOMIC_RELAXED, __HIP_MEMORY_SCOPE_AGENT);
          bool ok = (a >= tgt) && (b >= tgt) && (c >= tgt) && (d >= tgt);
          if (__all(ok)) break;
          __builtin_amdgcn_s_sleep(1);
          if (++spins > 150000){
            // fallback: acquire-loads (per-iter invalidate, guaranteed progress)
            for (;;){
              unsigned a2 = __hip_atomic_load(&flags[fs0], __ATOMIC_ACQUIRE, __HIP_MEMORY_SCOPE_AGENT);
              unsigned b2 = __hip_atomic_load(&flags[fs1], __ATOMIC_ACQUIRE, __HIP_MEMORY_SCOPE_AGENT);
              unsigned c2 = __hip_atomic_load(&flags[fs2], __ATOMIC_ACQUIRE, __HIP_MEMORY_SCOPE_AGENT);
              unsigned d2 = __hip_atomic_load(&flags[fs3], __ATOMIC_ACQUIRE, __HIP_MEMORY_SCOPE_AGENT);
              bool ok2 = (a2 >= tgt) && (b2 >= tgt) && (c2 >= tgt) && (d2 >= tgt);
              if (__all(ok2)) break;
              __builtin_amdgcn_s_sleep(8);
              if (++spins > 8000000) break;  // wrong answer beats a hang
            }
            break;
          }
        }
      }
      __syncthreads();
    }
  }
}

extern "C" void kernel_launch(void* const* d_in, const int* in_sizes, int n_in,
                              void* d_out, int out_size, void* d_ws, size_t ws_size,
                              hipStream_t stream) {
  const int*   tokens = (const int*)d_in[0];
  const float* emb = (const float*)d_in[1];
  const float* Wx  = (const float*)d_in[2];
  const float* bx  = (const float*)d_in[3];
  const float* Wh  = (const float*)d_in[4];
  const float* bh  = (const float*)d_in[5];
  const float* Wd  = (const float*)d_in[6];
  const float* bd  = (const float*)d_in[7];
  float* out = (float*)d_out;
  float* ws  = (float*)d_ws;

  // ws layout (floats): G 8388608 | H0 2097152 | Tops 2097152 | WhT 8388608 |
  //                     hb 32768 (2 layers x 2 x 8192) | flags 8192 (2 x 4096)
  float* G    = ws;
  float* H0   = ws + (size_t)8388608;
  float* Tops = ws + (size_t)10485760;
  float* WhT  = ws + (size_t)12582912;
  unsigned* hb    = (unsigned*)(ws + (size_t)20971520);
  unsigned* flags = (unsigned*)(ws + (size_t)21004288);

  (void)hipFuncSetAttribute((const void*)k_rec,
        hipFuncAttributeMaxDynamicSharedMemorySize, 101376);

  k_init<<<32,256,0,stream>>>(flags, (float*)hb);
  k_transpose<<<dim3(128,32,2), dim3(32,8), 0, stream>>>(Wh, WhT);

  // layer 0: G0 = emb[tok] @ Wx0 + (bx0+bh0)
  k_gemm<1,0><<<dim3(32,16),256,0,stream>>>(nullptr, Wx, bx, bh, tokens, emb, G, GATES);
  k_rec<<<256,256,101376,stream>>>(G, WhT, H0, hb, flags);

  // layer 1: G1 = H0 @ Wx1 + (bx1+bh1)
  k_gemm<0,0><<<dim3(32,16),256,0,stream>>>(H0, Wx + (size_t)1024*GATES, bx+GATES, bh+GATES,
                                            nullptr, nullptr, G, GATES);
  k_rec<<<256,256,101376,stream>>>(G, WhT + (size_t)GATES*HID, Tops,
                                   hb + 16384, flags + 4096);

  // final projection: out[b][t][v] = Tops[t*8+b] @ Wd + bd
  k_gemm<0,1><<<dim3(250,16),256,0,stream>>>(Tops, Wd, bd, nullptr, nullptr, nullptr, out, VOC);
}

// Round 8
// 4999.166 us; speedup vs baseline: 3.7010x; 1.1832x over previous
//
#include <hip/hip_runtime.h>
#include <cstdint>
#include <cstddef>

#define BATCH 8
#define SEQ   256
#define HID   1024
#define GATES 4096   // 4*HID
#define VOC   32000

typedef __attribute__((ext_vector_type(8))) short bf16x8;
typedef __attribute__((ext_vector_type(4))) float f32x4;

// ---------- helpers ----------
__device__ __forceinline__ float sigf(float x){ return 1.0f/(1.0f + __expf(-x)); }
__device__ __forceinline__ float tanhf_(float x){ return 1.0f - 2.0f/(__expf(2.0f*x) + 1.0f); }

__device__ __forceinline__ unsigned short f2bf(float x){
  union { float f; unsigned u; } v; v.f = x;
  unsigned r = v.u + 0x7fffu + ((v.u >> 16) & 1u);
  return (unsigned short)(r >> 16);
}
__device__ __forceinline__ float bf2f(unsigned short h){
  union { float f; unsigned u; } v; v.u = ((unsigned)h) << 16; return v.f;
}

// ---------- init: zero epoch flags + h ping-pong buffers ----------
__global__ void k_init(unsigned* __restrict__ flags, float* __restrict__ hb){
  int tid = blockIdx.x*blockDim.x + threadIdx.x;
  int nt = gridDim.x*blockDim.x;
  for (int i = tid; i < 2*256*16; i += nt) flags[i] = 0u;
  for (int i = tid; i < 2*2*BATCH*HID; i += nt) hb[i] = 0.0f;
}

// ---------- Wh transpose: WhT[l][n][k] = Wh[l][k][n] ----------
__global__ void k_transpose(const float* __restrict__ Wh, float* __restrict__ WhT){
  __shared__ float tile[32][33];
  int l = blockIdx.z;
  int n0 = blockIdx.x*32, k0 = blockIdx.y*32;
  const float* src = Wh  + (size_t)l*HID*GATES;
  float*       dst = WhT + (size_t)l*GATES*HID;
  int tx = threadIdx.x, ty = threadIdx.y;
  #pragma unroll
  for (int i=0;i<4;i++)
    tile[ty+i*8][tx] = src[(size_t)(k0+ty+i*8)*GATES + n0 + tx];
  __syncthreads();
  #pragma unroll
  for (int i=0;i<4;i++)
    dst[(size_t)(n0+ty+i*8)*HID + k0 + tx] = tile[tx][ty+i*8];
}

// ---------- f32 GEMM (pre-gate GEMMs only) ----------
template<int AMODE>
__global__ __launch_bounds__(256) void k_gemm(
    const float* __restrict__ A,
    const float* __restrict__ W,     // [1024][N] row-major
    const float* __restrict__ b1,
    const float* __restrict__ b2,
    const int*   __restrict__ tokens,
    const float* __restrict__ emb,
    float* __restrict__ C, int N)
{
  __shared__ float As[16*132];
  __shared__ float Bs[16*128];
  int tid = threadIdx.x;
  int m0 = blockIdx.y*128, n0 = blockIdx.x*128;

  int arow = tid >> 1;
  int akq  = (tid & 1) * 8;
  const float* aptr;
  { int gm = m0 + arow;
    if (AMODE==1){ int tt = gm>>3, bb = gm&7; aptr = emb + (size_t)tokens[bb*SEQ+tt]*1024; }
    else          aptr = A + (size_t)gm*1024; }

  int bk = tid >> 5;
  int bn = (tid & 31) * 4;
  const float* wptr = W + (size_t)bk*N + n0 + bn;

  int tx = tid & 15, ty = tid >> 4;
  float acc[8][8];
  #pragma unroll
  for (int i=0;i<8;i++){
    #pragma unroll
    for (int j=0;j<8;j++) acc[i][j] = 0.0f;
  }

  for (int k0=0;k0<1024;k0+=16){
    float4 av0 = *(const float4*)(aptr + k0 + akq);
    float4 av1 = *(const float4*)(aptr + k0 + akq + 4);
    float4 wv0 = *(const float4*)(wptr + (size_t)k0*N);
    float4 wv1 = *(const float4*)(wptr + (size_t)(k0+8)*N);
    __syncthreads();
    As[(akq+0)*132 + arow] = av0.x;
    As[(akq+1)*132 + arow] = av0.y;
    As[(akq+2)*132 + arow] = av0.z;
    As[(akq+3)*132 + arow] = av0.w;
    As[(akq+4)*132 + arow] = av1.x;
    As[(akq+5)*132 + arow] = av1.y;
    As[(akq+6)*132 + arow] = av1.z;
    As[(akq+7)*132 + arow] = av1.w;
    *(float4*)&Bs[bk*128 + bn]     = wv0;
    *(float4*)&Bs[(bk+8)*128 + bn] = wv1;
    __syncthreads();
    #pragma unroll
    for (int k=0;k<16;k++){
      float ra[8], rb[8];
      *(float4*)&ra[0] = *(float4*)&As[k*132 + ty*8];
      *(float4*)&ra[4] = *(float4*)&As[k*132 + ty*8 + 4];
      *(float4*)&rb[0] = *(float4*)&Bs[k*128 + tx*8];
      *(float4*)&rb[4] = *(float4*)&Bs[k*128 + tx*8 + 4];
      #pragma unroll
      for (int i=0;i<8;i++){
        #pragma unroll
        for (int j=0;j<8;j++)
          acc[i][j] = fmaf(ra[i], rb[j], acc[i][j]);
      }
    }
  }

  float bias[8];
  { int nb = n0 + tx*8;
    *(float4*)&bias[0] = *(const float4*)(b1 + nb);
    *(float4*)&bias[4] = *(const float4*)(b1 + nb + 4);
    if (b2){
      float4 c0 = *(const float4*)(b2 + nb);
      float4 c1 = *(const float4*)(b2 + nb + 4);
      bias[0]+=c0.x; bias[1]+=c0.y; bias[2]+=c0.z; bias[3]+=c0.w;
      bias[4]+=c1.x; bias[5]+=c1.y; bias[6]+=c1.z; bias[7]+=c1.w;
    }
  }
  #pragma unroll
  for (int i=0;i<8;i++){
    int gm = m0 + ty*8 + i;
    float* crow = C + (size_t)gm*N;
    float4 o0, o1;
    o0.x = acc[i][0]+bias[0]; o0.y = acc[i][1]+bias[1];
    o0.z = acc[i][2]+bias[2]; o0.w = acc[i][3]+bias[3];
    o1.x = acc[i][4]+bias[4]; o1.y = acc[i][5]+bias[5];
    o1.z = acc[i][6]+bias[6]; o1.w = acc[i][7]+bias[7];
    *(float4*)(crow + n0 + tx*8)     = o0;
    *(float4*)(crow + n0 + tx*8 + 4) = o1;
  }
}

// ---------- split-bf16 MFMA final GEMM ----------
// C = A@W + bd computed as Ah*Wh + Ah*Wl + Al*Wh (bf16 hi/lo split, f32 acc).
// Tile 256x128, BK=32, 4 waves (each 64 rows x 128 cols).
// LDS frag-linear: frag f, lane l holds its 8 bf16 at [f*1024 + l*8]
//   (A: row = l&15 of 16-row frag, k = (l>>4)*8+e ; B: col = l&15, same k).
// Output rows permuted: Tops row m=t*8+b -> out row (m&7)*256 + (m>>3).
__global__ __launch_bounds__(256) void k_gemm_mfma(
    const float* __restrict__ A,   // Tops [2048][1024]
    const float* __restrict__ W,   // Wd [1024][32000]
    const float* __restrict__ bd,  // [32000]
    float* __restrict__ C)         // out [2048][32000]
{
  __shared__ unsigned short AsH[16*1024], AsL[16*1024];
  __shared__ unsigned short BsH[8*1024],  BsL[8*1024];
  int tid = threadIdx.x;
  int m0 = blockIdx.y*256, n0 = blockIdx.x*128;
  int w = tid >> 6, l = tid & 63;
  int lrow = l & 15, kg = l >> 4;

  f32x4 acc[4][8];
  #pragma unroll
  for (int i=0;i<4;i++){
    #pragma unroll
    for (int j=0;j<8;j++) acc[i][j] = (f32x4){0.f,0.f,0.f,0.f};
  }

  int rA  = tid >> 3, fq = tid & 7;   // staging roles: 8 threads/row

  for (int kt=0; kt<32; ++kt){
    int k0 = kt*32;
    // global loads (before sync, overlap previous compute)
    float4 av[8];
    #pragma unroll
    for (int i=0;i<8;i++)
      av[i] = *(const float4*)(A + (size_t)(m0 + rA + 32*i)*1024 + k0 + fq*4);
    float4 wv[4];
    #pragma unroll
    for (int i=0;i<4;i++)
      wv[i] = *(const float4*)(W + (size_t)(k0 + rA)*VOC + n0 + fq*4 + 32*i);
    __syncthreads();
    // A -> frag-linear hi/lo
    #pragma unroll
    for (int i=0;i<8;i++){
      int r = rA + 32*i;
      int base = (r >> 4)*1024 + ((fq >> 1)*16 + (r & 15))*8 + (fq & 1)*4;
      float xs[4] = {av[i].x, av[i].y, av[i].z, av[i].w};
      unsigned long long ph = 0ull, pl = 0ull;
      #pragma unroll
      for (int c=0;c<4;c++){
        unsigned short h = f2bf(xs[c]);
        unsigned short lo = f2bf(xs[c] - bf2f(h));
        ph |= ((unsigned long long)h) << (16*c);
        pl |= ((unsigned long long)lo) << (16*c);
      }
      *(unsigned long long*)&AsH[base] = ph;
      *(unsigned long long*)&AsL[base] = pl;
    }
    // B -> frag-linear hi/lo (transpose to col-major frags)
    #pragma unroll
    for (int i=0;i<4;i++){
      float xs[4] = {wv[i].x, wv[i].y, wv[i].z, wv[i].w};
      #pragma unroll
      for (int c=0;c<4;c++){
        int col = fq*4 + 32*i + c;
        int idx = (col >> 4)*1024 + ((rA >> 3)*16 + (col & 15))*8 + (rA & 7);
        unsigned short h = f2bf(xs[c]);
        BsH[idx] = h;
        BsL[idx] = f2bf(xs[c] - bf2f(h));
      }
    }
    __syncthreads();
    // frag loads + 3-pass MFMA
    bf16x8 ah[4], al[4];
    #pragma unroll
    for (int i=0;i<4;i++){
      int fi = w*4 + i;
      ah[i] = *(const bf16x8*)&AsH[fi*1024 + l*8];
      al[i] = *(const bf16x8*)&AsL[fi*1024 + l*8];
    }
    #pragma unroll
    for (int jh=0;jh<2;jh++){
      bf16x8 bh[4], bl[4];
      #pragma unroll
      for (int j=0;j<4;j++){
        bh[j] = *(const bf16x8*)&BsH[(jh*4+j)*1024 + l*8];
        bl[j] = *(const bf16x8*)&BsL[(jh*4+j)*1024 + l*8];
      }
      #pragma unroll
      for (int i=0;i<4;i++){
        #pragma unroll
        for (int j=0;j<4;j++){
          f32x4 a = acc[i][jh*4+j];
          a = __builtin_amdgcn_mfma_f32_16x16x32_bf16(ah[i], bh[j], a, 0,0,0);
          a = __builtin_amdgcn_mfma_f32_16x16x32_bf16(ah[i], bl[j], a, 0,0,0);
          a = __builtin_amdgcn_mfma_f32_16x16x32_bf16(al[i], bh[j], a, 0,0,0);
          acc[i][jh*4+j] = a;
        }
      }
    }
    __syncthreads();
  }

  // epilogue: bias + permuted store (C/D map: col=lane&15, row=(lane>>4)*4+reg)
  int mbase = m0 + w*64 + kg*4;
  #pragma unroll
  for (int jj=0;jj<8;jj++){
    int gn = n0 + jj*16 + lrow;
    float bias = bd[gn];
    #pragma unroll
    for (int i=0;i<4;i++){
      #pragma unroll
      for (int r=0;r<4;r++){
        int m = mbase + i*16 + r;
        int crow = (m & 7)*SEQ + (m >> 3);
        C[(size_t)crow*VOC + gn] = acc[i][jj][r] + bias;
      }
    }
  }
}

// ---------- persistent recurrence v7: fence-free MALL message-passing ----------
__global__ __launch_bounds__(256) void k_rec(
    const float* __restrict__ G,
    const float* __restrict__ WhT,
    float* __restrict__ Hout,        // [2048][1024], row = t*8+b
    unsigned* __restrict__ hb,       // ping-pong [2][8][1024] as uint bits
    unsigned* __restrict__ flags)    // [256][16] epoch slots
{
  extern __shared__ float lds[];
  float* Wl  = lds;            // [16][1028]
  float* hl  = lds + 16448;    // [8][1028]
  float* gsc = lds + 24672;    // [4][64][2]
  int tid = threadIdx.x;
  int u0 = blockIdx.x*4;

  {
    int c = tid >> 4, ks = tid & 15;
    const float* src = WhT + ((size_t)(c>>2)*1024 + u0 + (c&3))*1024 + ks*64;
    float* dst = Wl + c*1028 + ks*64;
    #pragma unroll
    for (int i=0;i<16;i++)
      *(float4*)(dst + i*4) = *(const float4*)(src + i*4);
  }

  const int wv = tid >> 6, ln = tid & 63;
  const int db = ln >> 3, dc = ln & 7;
  const int kbase = wv*256;
  const int sb = tid & 7, sk = (tid >> 3)*32;
  const int cb = tid >> 2, cj = tid & 3;
  const int fs0 = tid*16, fs1 = (tid+64)*16, fs2 = (tid+128)*16, fs3 = (tid+192)*16;
  float creg = 0.0f;

  for (int t=0;t<SEQ;t++){
    {
      const float* src = (const float*)(hb + (t&1)*8192) + sb*1024 + sk;
      float4 r0,r1,r2,r3,r4,r5,r6,r7;
      asm volatile(
        "global_load_dwordx4 %0, %8, off sc0 sc1\n\t"
        "global_load_dwordx4 %1, %8, off offset:16 sc0 sc1\n\t"
        "global_load_dwordx4 %2, %8, off offset:32 sc0 sc1\n\t"
        "global_load_dwordx4 %3, %8, off offset:48 sc0 sc1\n\t"
        "global_load_dwordx4 %4, %8, off offset:64 sc0 sc1\n\t"
        "global_load_dwordx4 %5, %8, off offset:80 sc0 sc1\n\t"
        "global_load_dwordx4 %6, %8, off offset:96 sc0 sc1\n\t"
        "global_load_dwordx4 %7, %8, off offset:112 sc0 sc1\n\t"
        "s_waitcnt vmcnt(0)"
        : "=&v"(r0),"=&v"(r1),"=&v"(r2),"=&v"(r3),
          "=&v"(r4),"=&v"(r5),"=&v"(r6),"=&v"(r7)
        : "v"(src)
        : "memory");
      float* dst = hl + sb*1028 + sk;
      *(float4*)(dst+ 0)=r0; *(float4*)(dst+ 4)=r1;
      *(float4*)(dst+ 8)=r2; *(float4*)(dst+12)=r3;
      *(float4*)(dst+16)=r4; *(float4*)(dst+20)=r5;
      *(float4*)(dst+24)=r6; *(float4*)(dst+28)=r7;
    }
    float gp0=0.f,gp1=0.f,gp2=0.f,gp3=0.f;
    if (tid < 32){
      const float* gp = G + ((size_t)t*8 + cb)*GATES + u0 + cj;
      gp0 = gp[0]; gp1 = gp[1024]; gp2 = gp[2048]; gp3 = gp[3072];
    }
    __syncthreads();

    float a0 = 0.f, a1 = 0.f;
    const float* hp = hl + db*1028 + kbase;
    const float* w0 = Wl + dc*1028 + kbase;
    const float* w1 = Wl + (dc+8)*1028 + kbase;
    #pragma unroll 4
    for (int k=0;k<256;k+=4){
      float4 hv = *(const float4*)(hp + k);
      float4 x0 = *(const float4*)(w0 + k);
      float4 x1 = *(const float4*)(w1 + k);
      a0 = fmaf(hv.x,x0.x,a0); a0 = fmaf(hv.y,x0.y,a0);
      a0 = fmaf(hv.z,x0.z,a0); a0 = fmaf(hv.w,x0.w,a0);
      a1 = fmaf(hv.x,x1.x,a1); a1 = fmaf(hv.y,x1.y,a1);
      a1 = fmaf(hv.z,x1.z,a1); a1 = fmaf(hv.w,x1.w,a1);
    }
    gsc[wv*128 + ln*2 + 0] = a0;
    gsc[wv*128 + ln*2 + 1] = a1;
    __syncthreads();

    if (tid < 32){
      int b0 = (cb*8 + cj)*2, b1i = (cb*8 + 4 + cj)*2;
      float xi = gp0, xf = gp1, xg = gp2, xo = gp3;
      #pragma unroll
      for (int w=0;w<4;w++){
        xi += gsc[w*128 + b0];
        xf += gsc[w*128 + b1i];
        xg += gsc[w*128 + b0 + 1];
        xo += gsc[w*128 + b1i + 1];
      }
      float iv = sigf(xi), fv = sigf(xf), ov = sigf(xo), gv = tanhf_(xg);
      creg = fv*creg + iv*gv;
      float hv = ov * tanhf_(creg);
      if (t < SEQ-1){
        (void)__hip_atomic_exchange(&hb[((t+1)&1)*8192 + cb*1024 + u0 + cj],
                                    __float_as_uint(hv), __ATOMIC_RELAXED,
                                    __HIP_MEMORY_SCOPE_AGENT);
      }
      Hout[((size_t)t*8 + cb)*HID + u0 + cj] = hv;
    }

    if (t < SEQ-1){
      if (tid < 64){
        if (tid == 0){
          asm volatile("s_waitcnt vmcnt(0)" ::: "memory");
          (void)__hip_atomic_exchange(&flags[blockIdx.x*16], (unsigned)(t+1),
                                      __ATOMIC_RELAXED, __HIP_MEMORY_SCOPE_AGENT);
        }
        unsigned tgt = (unsigned)(t+1);
        int spins = 0;
        for (;;){
          unsigned a = __hip_atomic_load(&flags[fs0], __ATOMIC_RELAXED, __HIP_MEMORY_SCOPE_AGENT);
          unsigned b = __hip_atomic_load(&flags[fs1], __ATOMIC_RELAXED, __HIP_MEMORY_SCOPE_AGENT);
          unsigned c = __hip_atomic_load(&flags[fs2], __ATOMIC_RELAXED, __HIP_MEMORY_SCOPE_AGENT);
          unsigned d = __hip_atomic_load(&flags[fs3], __ATOMIC_RELAXED, __HIP_MEMORY_SCOPE_AGENT);
          bool ok = (a >= tgt) && (b >= tgt) && (c >= tgt) && (d >= tgt);
          if (__all(ok)) break;
          __builtin_amdgcn_s_sleep(1);
          if (++spins > 150000){
            for (;;){
              unsigned a2 = __hip_atomic_load(&flags[fs0], __ATOMIC_ACQUIRE, __HIP_MEMORY_SCOPE_AGENT);
              unsigned b2 = __hip_atomic_load(&flags[fs1], __ATOMIC_ACQUIRE, __HIP_MEMORY_SCOPE_AGENT);
              unsigned c2 = __hip_atomic_load(&flags[fs2], __ATOMIC_ACQUIRE, __HIP_MEMORY_SCOPE_AGENT);
              unsigned d2 = __hip_atomic_load(&flags[fs3], __ATOMIC_ACQUIRE, __HIP_MEMORY_SCOPE_AGENT);
              bool ok2 = (a2 >= tgt) && (b2 >= tgt) && (c2 >= tgt) && (d2 >= tgt);
              if (__all(ok2)) break;
              __builtin_amdgcn_s_sleep(8);
              if (++spins > 8000000) break;
            }
            break;
          }
        }
      }
      __syncthreads();
    }
  }
}

extern "C" void kernel_launch(void* const* d_in, const int* in_sizes, int n_in,
                              void* d_out, int out_size, void* d_ws, size_t ws_size,
                              hipStream_t stream) {
  const int*   tokens = (const int*)d_in[0];
  const float* emb = (const float*)d_in[1];
  const float* Wx  = (const float*)d_in[2];
  const float* bx  = (const float*)d_in[3];
  const float* Wh  = (const float*)d_in[4];
  const float* bh  = (const float*)d_in[5];
  const float* Wd  = (const float*)d_in[6];
  const float* bd  = (const float*)d_in[7];
  float* out = (float*)d_out;
  float* ws  = (float*)d_ws;

  // ws layout (floats): G 8388608 | H0 2097152 | Tops 2097152 | WhT 8388608 |
  //                     hb 32768 (2 layers x 2 x 8192) | flags 8192 (2 x 4096)
  float* G    = ws;
  float* H0   = ws + (size_t)8388608;
  float* Tops = ws + (size_t)10485760;
  float* WhT  = ws + (size_t)12582912;
  unsigned* hb    = (unsigned*)(ws + (size_t)20971520);
  unsigned* flags = (unsigned*)(ws + (size_t)21004288);

  (void)hipFuncSetAttribute((const void*)k_rec,
        hipFuncAttributeMaxDynamicSharedMemorySize, 101376);

  k_init<<<32,256,0,stream>>>(flags, (float*)hb);
  k_transpose<<<dim3(128,32,2), dim3(32,8), 0, stream>>>(Wh, WhT);

  // layer 0: G0 = emb[tok] @ Wx0 + (bx0+bh0)
  k_gemm<1><<<dim3(32,16),256,0,stream>>>(nullptr, Wx, bx, bh, tokens, emb, G, GATES);
  k_rec<<<256,256,101376,stream>>>(G, WhT, H0, hb, flags);

  // layer 1: G1 = H0 @ Wx1 + (bx1+bh1)
  k_gemm<0><<<dim3(32,16),256,0,stream>>>(H0, Wx + (size_t)1024*GATES, bx+GATES, bh+GATES,
                                          nullptr, nullptr, G, GATES);
  k_rec<<<256,256,101376,stream>>>(G, WhT + (size_t)GATES*HID, Tops,
                                   hb + 16384, flags + 4096);

  // final projection (split-bf16 MFMA): out[b][t][v] = Tops[t*8+b] @ Wd + bd
  k_gemm_mfma<<<dim3(250,8),256,0,stream>>>(Tops, Wd, bd, out);
}